// Round 1
// baseline (1965.504 us; speedup 1.0000x reference)
//
#include <hip/hip_runtime.h>
#include <hip/hip_bf16.h>

typedef __hip_bfloat16 bf16;
typedef unsigned int u32;

#define HWSZ 65536u   // 256*256

__device__ __forceinline__ float b2f_lo(u32 w){ return __uint_as_float(w << 16); }
__device__ __forceinline__ float b2f_hi(u32 w){ return __uint_as_float(w & 0xffff0000u); }
__device__ __forceinline__ float b2f(bf16 v){ return __bfloat162float(v); }
__device__ __forceinline__ bf16 f2b(float v){ return __float2bfloat16(v); }

__device__ __forceinline__ u32 f2bbits(float f){
  u32 x = __float_as_uint(f);
  return ((x + 0x7fffu + ((x >> 16) & 1u)) >> 16) & 0xffffu;  // RNE
}

__device__ __forceinline__ void unpack8(uint4 v, float* f){
  f[0]=b2f_lo(v.x); f[1]=b2f_hi(v.x);
  f[2]=b2f_lo(v.y); f[3]=b2f_hi(v.y);
  f[4]=b2f_lo(v.z); f[5]=b2f_hi(v.z);
  f[6]=b2f_lo(v.w); f[7]=b2f_hi(v.w);
}

// ---------------- K1: 1x1 qkv projection: x[16,64,256,256] fp32 -> qkv1[16,192,HW] bf16
__global__ __launch_bounds__(256) void k1_pointwise(
    const float* __restrict__ x, const float* __restrict__ wq, bf16* __restrict__ qkv1){
  int t = threadIdx.x;
  u32 pix = blockIdx.x * 256u + t;          // 0 .. 16*65536-1
  u32 b = pix >> 16, hw = pix & 65535u;
  const float* xp = x + (size_t)b * 64 * HWSZ + hw;
  float xr[64];
  #pragma unroll
  for (int c = 0; c < 64; c++) xr[c] = xp[(size_t)c * HWSZ];
  bf16* op = qkv1 + (size_t)b * 192 * HWSZ + hw;
  for (int o = 0; o < 192; o++){
    const float* wr = wq + o * 64;          // wave-uniform -> s_load
    float a0 = 0.f, a1 = 0.f, a2 = 0.f, a3 = 0.f;
    #pragma unroll
    for (int c = 0; c < 64; c += 4){
      a0 += xr[c]   * wr[c];
      a1 += xr[c+1] * wr[c+1];
      a2 += xr[c+2] * wr[c+2];
      a3 += xr[c+3] * wr[c+3];
    }
    op[(size_t)o * HWSZ] = f2b((a0 + a1) + (a2 + a3));
  }
}

// ---------------- K2: 3x3 depthwise conv (pad 1) + tokenize
// qkv1[b,192,256,256] bf16 -> tok[g=3][b=16][h=8][i=64][d=8192] bf16
__global__ __launch_bounds__(256) void k2_dwconv_tok(
    const bf16* __restrict__ qkv1, const float* __restrict__ wdw, bf16* __restrict__ tok){
  int t = threadIdx.x;
  u32 bid = blockIdx.x;                     // b*1536 + g*512 + h*64 + win
  u32 win = bid & 63u, h = (bid >> 6) & 7u, g = (bid >> 9) % 3u, b = bid / 1536u;
  u32 wy = win >> 3, wx = win & 7u;
  int y0 = wy * 32 + h * 4, x0 = wx * 32;

  __shared__ bf16 tile[13056];              // [ch=64][row=6][col=34]
  __shared__ float wds[576];                // [ch=64][tap=9]
  for (int idx = t; idx < 576; idx += 256) wds[idx] = wdw[g * 576u + idx];
  const bf16* src = qkv1 + ((size_t)b * 192 + g * 64) * HWSZ;
  for (int lin = t; lin < 13056; lin += 256){
    int ch = lin / 204, r2 = lin - ch * 204;
    int row = r2 / 34, col = r2 - row * 34;
    int y = y0 - 1 + row, xx = x0 - 1 + col;
    bf16 v = f2b(0.f);
    if ((u32)y < 256u && (u32)xx < 256u) v = src[((size_t)ch << 16) + (y << 8) + xx];
    tile[lin] = v;
  }
  __syncthreads();

  int ch = t & 63;                          // d = r*256+t -> ch = t&63 (constant over r)
  float wreg[9];
  #pragma unroll
  for (int k = 0; k < 9; k++) wreg[k] = wds[ch * 9 + k];
  const bf16* tbase = &tile[ch * 204];
  size_t obase = ((((size_t)g * 16 + b) * 8 + h) * 64 + win) * 8192;

  for (int r = 0; r < 32; r++){
    int d = r * 256 + t;
    int p1 = (d >> 6) & 31, p0 = d >> 11;
    const bf16* tp = tbase + p0 * 34 + p1;
    float acc = 0.f;
    #pragma unroll
    for (int dy = 0; dy < 3; dy++)
      #pragma unroll
      for (int dx = 0; dx < 3; dx++)
        acc += b2f(tp[dy * 34 + dx]) * wreg[dy * 3 + dx];
    tok[obase + d] = f2b(acc);
  }
}

// ---------------- K3: sim partials: q.k over d-quarter -> sim4[part=4][b][h][64][64] fp32
__global__ __launch_bounds__(256) void k3_sim(
    const bf16* __restrict__ tok, float* __restrict__ sim4){
  int t = threadIdx.x;
  u32 bid = blockIdx.x;                     // b*32 + h*4 + part
  u32 part = bid & 3u, h = (bid >> 2) & 7u, b = bid >> 5;
  int ti = t & 15, tj = t >> 4;
  const bf16* qb = tok + ((size_t)(((0 * 16 + b) * 8 + h) * 64)) * 8192;
  const bf16* kb = tok + ((size_t)(((1 * 16 + b) * 8 + h) * 64)) * 8192;

  __shared__ float qc[64 * 68];             // [dd][i], stride 68 (pad for banks + b128 align)
  __shared__ float kc[64 * 68];
  float acc[4][4] = {{0.f}};

  for (int cc = 0; cc < 32; cc++){
    int d0 = part * 2048 + cc * 64;
    __syncthreads();
    #pragma unroll
    for (int rr = 0; rr < 2; rr++){
      int lin = (rr * 256 + t) * 8;         // element within 64i x 64dd chunk
      int i = lin >> 6, dd = lin & 63;
      uint4 qv = *(const uint4*)(qb + (size_t)i * 8192 + d0 + dd);
      uint4 kv = *(const uint4*)(kb + (size_t)i * 8192 + d0 + dd);
      float qf[8], kf[8];
      unpack8(qv, qf); unpack8(kv, kf);
      #pragma unroll
      for (int u = 0; u < 8; u++){
        qc[(dd + u) * 68 + i] = qf[u];
        kc[(dd + u) * 68 + i] = kf[u];
      }
    }
    __syncthreads();
    for (int dd = 0; dd < 64; dd++){
      float4 qv = *(const float4*)&qc[dd * 68 + ti * 4];
      float4 kv = *(const float4*)&kc[dd * 68 + tj * 4];
      acc[0][0] += qv.x * kv.x; acc[0][1] += qv.x * kv.y; acc[0][2] += qv.x * kv.z; acc[0][3] += qv.x * kv.w;
      acc[1][0] += qv.y * kv.x; acc[1][1] += qv.y * kv.y; acc[1][2] += qv.y * kv.z; acc[1][3] += qv.y * kv.w;
      acc[2][0] += qv.z * kv.x; acc[2][1] += qv.z * kv.y; acc[2][2] += qv.z * kv.z; acc[2][3] += qv.z * kv.w;
      acc[3][0] += qv.w * kv.x; acc[3][1] += qv.w * kv.y; acc[3][2] += qv.w * kv.z; acc[3][3] += qv.w * kv.w;
    }
  }
  float* sp = sim4 + ((((size_t)part * 16 + b) * 8 + h) * 64) * 64;
  #pragma unroll
  for (int ii = 0; ii < 4; ii++)
    #pragma unroll
    for (int jj = 0; jj < 4; jj++)
      sp[(ti * 4 + ii) * 64 + (tj * 4 + jj)] = acc[ii][jj];
}

// ---------------- K4: combine partials, scale, +pos_emb, softmax -> attn[b][h][64][64] fp32
__global__ __launch_bounds__(64) void k4_softmax(
    const float* __restrict__ sim4, const float* __restrict__ pos, float* __restrict__ attn){
  int j = threadIdx.x;
  u32 bid = blockIdx.x;                     // b*512 + h*64 + i
  u32 i = bid & 63u, h = (bid >> 6) & 7u, b = bid >> 9;
  size_t o = (((size_t)b * 8 + h) * 64 + i) * 64 + j;
  const size_t pstride = (size_t)16 * 8 * 64 * 64;
  float s = sim4[o] + sim4[o + pstride] + sim4[o + 2 * pstride] + sim4[o + 3 * pstride];
  s = s * 0.011048543456039806f + pos[(((size_t)h * 64) + i) * 64 + j];
  float m = s;
  #pragma unroll
  for (int off = 32; off; off >>= 1) m = fmaxf(m, __shfl_xor(m, off));
  float e = __expf(s - m);
  float sum = e;
  #pragma unroll
  for (int off = 32; off; off >>= 1) sum += __shfl_xor(sum, off);
  attn[o] = e / sum;
}

// ---------------- K5: out_tok[b,h,i,d] = sum_j attn[b,h,i,j] * v_tok[b,h,j,d]
__global__ __launch_bounds__(256) void k5_av(
    const bf16* __restrict__ tok, const float* __restrict__ attn, bf16* __restrict__ otok){
  int t = threadIdx.x;
  u32 bid = blockIdx.x;                     // b*64 + h*8 + io
  u32 io = bid & 7u, h = (bid >> 3) & 7u, b = bid >> 6;
  const bf16* vb = tok + ((size_t)(((2 * 16 + b) * 8 + h) * 64)) * 8192;
  const float* ab = attn + (((size_t)b * 8 + h) * 64 + io * 8) * 64;   // uniform -> s_load
  bf16* ob = otok + ((((size_t)b * 8 + h) * 64 + io * 8)) * 8192;

  for (int g = 0; g < 4; g++){
    int d = g * 2048 + t * 8;
    float acc[8][8];
    #pragma unroll
    for (int ii = 0; ii < 8; ii++)
      #pragma unroll
      for (int u = 0; u < 8; u++) acc[ii][u] = 0.f;
    for (int j = 0; j < 64; j++){
      uint4 vv = *(const uint4*)(vb + (size_t)j * 8192 + d);
      float vf[8];
      unpack8(vv, vf);
      #pragma unroll
      for (int ii = 0; ii < 8; ii++){
        float a = ab[ii * 64 + j];
        #pragma unroll
        for (int u = 0; u < 8; u++) acc[ii][u] += a * vf[u];
      }
    }
    #pragma unroll
    for (int ii = 0; ii < 8; ii++){
      uint4 w;
      w.x = f2bbits(acc[ii][0]) | (f2bbits(acc[ii][1]) << 16);
      w.y = f2bbits(acc[ii][2]) | (f2bbits(acc[ii][3]) << 16);
      w.z = f2bbits(acc[ii][4]) | (f2bbits(acc[ii][5]) << 16);
      w.w = f2bbits(acc[ii][6]) | (f2bbits(acc[ii][7]) << 16);
      *(uint4*)(ob + (size_t)ii * 8192 + d) = w;
    }
  }
}

// ---------------- K6: un-tokenize + 1x1 proj + bias -> out[16,64,256,256] fp32
__global__ __launch_bounds__(256) void k6_proj(
    const bf16* __restrict__ otok, const float* __restrict__ wp,
    const float* __restrict__ bp, float* __restrict__ out){
  int t = threadIdx.x;
  u32 pix = blockIdx.x * 256u + t;
  u32 b = pix >> 16, hw = pix & 65535u;
  int y = hw >> 8, xx = hw & 255;
  int p0 = y & 31, h = p0 >> 2;
  int i = ((y >> 5) << 3) + (xx >> 5), p1 = xx & 31;
  const bf16* ip = otok + ((((size_t)b * 8 + h) * 64 + i)) * 8192 + (p0 & 3) * 2048 + p1 * 64;
  float xr[64];
  #pragma unroll
  for (int u = 0; u < 8; u++){
    uint4 v = *(const uint4*)(ip + u * 8);
    unpack8(v, &xr[u * 8]);
  }
  float* op = out + (size_t)b * 64 * HWSZ + hw;
  for (int o = 0; o < 64; o++){
    const float* wr = wp + o * 64;          // uniform -> s_load
    float a0 = bp[o], a1 = 0.f, a2 = 0.f, a3 = 0.f;
    #pragma unroll
    for (int c = 0; c < 64; c += 4){
      a0 += xr[c]   * wr[c];
      a1 += xr[c+1] * wr[c+1];
      a2 += xr[c+2] * wr[c+2];
      a3 += xr[c+3] * wr[c+3];
    }
    op[(size_t)o * HWSZ] = (a0 + a1) + (a2 + a3);
  }
}

extern "C" void kernel_launch(void* const* d_in, const int* in_sizes, int n_in,
                              void* d_out, int out_size, void* d_ws, size_t ws_size,
                              hipStream_t stream){
  const float* x   = (const float*)d_in[0];
  const float* wq  = (const float*)d_in[1];
  const float* wdw = (const float*)d_in[2];
  const float* wp  = (const float*)d_in[3];
  const float* bp  = (const float*)d_in[4];
  const float* pos = (const float*)d_in[5];
  float* out = (float*)d_out;
  (void)in_sizes; (void)n_in; (void)out_size; (void)ws_size;

  char* ws = (char*)d_ws;
  // region A [0, 402653184): qkv1 during K1/K2; then reused: otok @0 (134MB), sim4, attn
  bf16*  qkv1 = (bf16*)ws;
  bf16*  tok  = (bf16*)(ws + 402653184u);   // 402,653,184 B
  bf16*  otok = (bf16*)ws;                  // reuse of region A (K2 consumer done)
  float* sim4 = (float*)(ws + 134217728u);  // 8,388,608 B  (4 partials)
  float* attn = (float*)(ws + 142606336u);  // 2,097,152 B

  k1_pointwise<<<dim3(4096),  dim3(256), 0, stream>>>(x, wq, qkv1);
  k2_dwconv_tok<<<dim3(24576), dim3(256), 0, stream>>>(qkv1, wdw, tok);
  k3_sim<<<dim3(512),   dim3(256), 0, stream>>>(tok, sim4);
  k4_softmax<<<dim3(8192), dim3(64), 0, stream>>>(sim4, pos, attn);
  k5_av<<<dim3(1024),  dim3(256), 0, stream>>>(tok, attn, otok);
  k6_proj<<<dim3(4096), dim3(256), 0, stream>>>(otok, wp, bp, out);
}

// Round 2
// 1298.877 us; speedup vs baseline: 1.5132x; 1.5132x over previous
//
#include <hip/hip_runtime.h>
#include <hip/hip_bf16.h>

typedef __hip_bfloat16 bf16;
typedef unsigned int u32;
typedef __attribute__((ext_vector_type(8))) short bf16x8;
typedef __attribute__((ext_vector_type(4))) float f32x4;

#define HWSZ 65536u   // 256*256

__device__ __forceinline__ float b2f_lo(u32 w){ return __uint_as_float(w << 16); }
__device__ __forceinline__ float b2f_hi(u32 w){ return __uint_as_float(w & 0xffff0000u); }
__device__ __forceinline__ float b2f(bf16 v){ return __bfloat162float(v); }
__device__ __forceinline__ bf16 f2b(float v){ return __float2bfloat16(v); }

__device__ __forceinline__ u32 f2bbits(float f){
  u32 x = __float_as_uint(f);
  return ((x + 0x7fffu + ((x >> 16) & 1u)) >> 16) & 0xffffu;  // RNE
}

__device__ __forceinline__ void unpack8(uint4 v, float* f){
  f[0]=b2f_lo(v.x); f[1]=b2f_hi(v.x);
  f[2]=b2f_lo(v.y); f[3]=b2f_hi(v.y);
  f[4]=b2f_lo(v.z); f[5]=b2f_hi(v.z);
  f[6]=b2f_lo(v.w); f[7]=b2f_hi(v.w);
}

union ABu { u32 u[4]; bf16x8 v; uint4 q; };

// ---------------- K1 (MFMA): qkv1[b,192,HW] bf16 = W[192,64] x X[64,HW]
// block: 256 thr = 4 waves; tile 192 och x 128 pix; LDS X as [c8][pix][8ch]
__global__ __launch_bounds__(256) void k1_mfma(
    const float* __restrict__ x, const float* __restrict__ wq, bf16* __restrict__ qkv1){
  __shared__ uint4 xs[1024];                 // 8 c8-groups * 128 pix, 16B each
  int t = threadIdx.x;
  int lane = t & 63, w = t >> 6;
  u32 pix0 = blockIdx.x * 128u;
  u32 b = pix0 >> 16, hw0 = pix0 & 65535u;

  { // stage X: fp32 -> bf16, [c8][pix][j]
    int pix = t & 127, half = t >> 7;
    const float* xp = x + (size_t)b * 64 * HWSZ + hw0 + pix;
    #pragma unroll
    for (int g = 0; g < 4; g++){
      int c8 = half * 4 + g;
      ABu pk;
      #pragma unroll
      for (int j = 0; j < 4; j++){
        float f0 = xp[(size_t)(c8 * 8 + 2 * j)     * HWSZ];
        float f1 = xp[(size_t)(c8 * 8 + 2 * j + 1) * HWSZ];
        pk.u[j] = f2bbits(f0) | (f2bbits(f1) << 16);
      }
      xs[c8 * 128 + pix] = pk.q;
    }
  }

  int r16 = lane & 15, g4 = lane >> 4;
  // A fragments: W rows, lane holds A[m=r16][k=g4*8+j], kt in {0,1} (k-halves)
  bf16x8 af[3][2];
  #pragma unroll
  for (int ot = 0; ot < 3; ot++){
    int och = (w * 3 + ot) * 16 + r16;
    #pragma unroll
    for (int kt = 0; kt < 2; kt++){
      const float* wr = wq + och * 64 + kt * 32 + g4 * 8;
      ABu pk;
      #pragma unroll
      for (int j = 0; j < 4; j++)
        pk.u[j] = f2bbits(wr[2 * j]) | (f2bbits(wr[2 * j + 1]) << 16);
      af[ot][kt] = pk.v;
    }
  }
  __syncthreads();

  f32x4 acc[3][8];
  #pragma unroll
  for (int ot = 0; ot < 3; ot++)
    #pragma unroll
    for (int pt = 0; pt < 8; pt++) acc[ot][pt] = (f32x4){0.f,0.f,0.f,0.f};

  #pragma unroll
  for (int pt = 0; pt < 8; pt++){
    uint4 u0 = xs[(0 * 4 + g4) * 128 + pt * 16 + r16];
    uint4 u1 = xs[(1 * 4 + g4) * 128 + pt * 16 + r16];
    bf16x8 b0 = *reinterpret_cast<bf16x8*>(&u0);
    bf16x8 b1 = *reinterpret_cast<bf16x8*>(&u1);
    #pragma unroll
    for (int ot = 0; ot < 3; ot++){
      acc[ot][pt] = __builtin_amdgcn_mfma_f32_16x16x32_bf16(af[ot][0], b0, acc[ot][pt], 0, 0, 0);
      acc[ot][pt] = __builtin_amdgcn_mfma_f32_16x16x32_bf16(af[ot][1], b1, acc[ot][pt], 0, 0, 0);
    }
  }

  bf16* op = qkv1 + (size_t)b * 192 * HWSZ + hw0;
  #pragma unroll
  for (int ot = 0; ot < 3; ot++){
    int ochb = (w * 3 + ot) * 16 + g4 * 4;
    #pragma unroll
    for (int pt = 0; pt < 8; pt++)
      #pragma unroll
      for (int r = 0; r < 4; r++)
        op[(size_t)(ochb + r) * HWSZ + pt * 16 + r16] = f2b(acc[ot][pt][r]);
  }
}

// ---------------- K2: 3x3 depthwise conv (pad 1) + tokenize (unchanged)
__global__ __launch_bounds__(256) void k2_dwconv_tok(
    const bf16* __restrict__ qkv1, const float* __restrict__ wdw, bf16* __restrict__ tok){
  int t = threadIdx.x;
  u32 bid = blockIdx.x;                     // b*1536 + g*512 + h*64 + win
  u32 win = bid & 63u, h = (bid >> 6) & 7u, g = (bid >> 9) % 3u, b = bid / 1536u;
  u32 wy = win >> 3, wx = win & 7u;
  int y0 = wy * 32 + h * 4, x0 = wx * 32;

  __shared__ bf16 tile[13056];              // [ch=64][row=6][col=34]
  __shared__ float wds[576];                // [ch=64][tap=9]
  for (int idx = t; idx < 576; idx += 256) wds[idx] = wdw[g * 576u + idx];
  const bf16* src = qkv1 + ((size_t)b * 192 + g * 64) * HWSZ;
  for (int lin = t; lin < 13056; lin += 256){
    int ch = lin / 204, r2 = lin - ch * 204;
    int row = r2 / 34, col = r2 - row * 34;
    int y = y0 - 1 + row, xx = x0 - 1 + col;
    bf16 v = f2b(0.f);
    if ((u32)y < 256u && (u32)xx < 256u) v = src[((size_t)ch << 16) + (y << 8) + xx];
    tile[lin] = v;
  }
  __syncthreads();

  int ch = t & 63;
  float wreg[9];
  #pragma unroll
  for (int k = 0; k < 9; k++) wreg[k] = wds[ch * 9 + k];
  const bf16* tbase = &tile[ch * 204];
  size_t obase = ((((size_t)g * 16 + b) * 8 + h) * 64 + win) * 8192;

  for (int r = 0; r < 32; r++){
    int d = r * 256 + t;
    int p1 = (d >> 6) & 31, p0 = d >> 11;
    const bf16* tp = tbase + p0 * 34 + p1;
    float acc = 0.f;
    #pragma unroll
    for (int dy = 0; dy < 3; dy++)
      #pragma unroll
      for (int dx = 0; dx < 3; dx++)
        acc += b2f(tp[dy * 34 + dx]) * wreg[dy * 3 + dx];
    tok[obase + d] = f2b(acc);
  }
}

// ---------------- K3: sim partials (unchanged fp32)
__global__ __launch_bounds__(256) void k3_sim(
    const bf16* __restrict__ tok, float* __restrict__ sim4){
  int t = threadIdx.x;
  u32 bid = blockIdx.x;
  u32 part = bid & 3u, h = (bid >> 2) & 7u, b = bid >> 5;
  int ti = t & 15, tj = t >> 4;
  const bf16* qb = tok + ((size_t)(((0 * 16 + b) * 8 + h) * 64)) * 8192;
  const bf16* kb = tok + ((size_t)(((1 * 16 + b) * 8 + h) * 64)) * 8192;

  __shared__ float qc[64 * 68];
  __shared__ float kc[64 * 68];
  float acc[4][4] = {{0.f}};

  for (int cc = 0; cc < 32; cc++){
    int d0 = part * 2048 + cc * 64;
    __syncthreads();
    #pragma unroll
    for (int rr = 0; rr < 2; rr++){
      int lin = (rr * 256 + t) * 8;
      int i = lin >> 6, dd = lin & 63;
      uint4 qv = *(const uint4*)(qb + (size_t)i * 8192 + d0 + dd);
      uint4 kv = *(const uint4*)(kb + (size_t)i * 8192 + d0 + dd);
      float qf[8], kf[8];
      unpack8(qv, qf); unpack8(kv, kf);
      #pragma unroll
      for (int u = 0; u < 8; u++){
        qc[(dd + u) * 68 + i] = qf[u];
        kc[(dd + u) * 68 + i] = kf[u];
      }
    }
    __syncthreads();
    for (int dd = 0; dd < 64; dd++){
      float4 qv = *(const float4*)&qc[dd * 68 + ti * 4];
      float4 kv = *(const float4*)&kc[dd * 68 + tj * 4];
      acc[0][0] += qv.x * kv.x; acc[0][1] += qv.x * kv.y; acc[0][2] += qv.x * kv.z; acc[0][3] += qv.x * kv.w;
      acc[1][0] += qv.y * kv.x; acc[1][1] += qv.y * kv.y; acc[1][2] += qv.y * kv.z; acc[1][3] += qv.y * kv.w;
      acc[2][0] += qv.z * kv.x; acc[2][1] += qv.z * kv.y; acc[2][2] += qv.z * kv.z; acc[2][3] += qv.z * kv.w;
      acc[3][0] += qv.w * kv.x; acc[3][1] += qv.w * kv.y; acc[3][2] += qv.w * kv.z; acc[3][3] += qv.w * kv.w;
    }
  }
  float* sp = sim4 + ((((size_t)part * 16 + b) * 8 + h) * 64) * 64;
  #pragma unroll
  for (int ii = 0; ii < 4; ii++)
    #pragma unroll
    for (int jj = 0; jj < 4; jj++)
      sp[(ti * 4 + ii) * 64 + (tj * 4 + jj)] = acc[ii][jj];
}

// ---------------- K4: softmax (unchanged)
__global__ __launch_bounds__(64) void k4_softmax(
    const float* __restrict__ sim4, const float* __restrict__ pos, float* __restrict__ attn){
  int j = threadIdx.x;
  u32 bid = blockIdx.x;
  u32 i = bid & 63u, h = (bid >> 6) & 7u, b = bid >> 9;
  size_t o = (((size_t)b * 8 + h) * 64 + i) * 64 + j;
  const size_t pstride = (size_t)16 * 8 * 64 * 64;
  float s = sim4[o] + sim4[o + pstride] + sim4[o + 2 * pstride] + sim4[o + 3 * pstride];
  s = s * 0.011048543456039806f + pos[(((size_t)h * 64) + i) * 64 + j];
  float m = s;
  #pragma unroll
  for (int off = 32; off; off >>= 1) m = fmaxf(m, __shfl_xor(m, off));
  float e = __expf(s - m);
  float sum = e;
  #pragma unroll
  for (int off = 32; off; off >>= 1) sum += __shfl_xor(sum, off);
  attn[o] = e / sum;
}

// ---------------- K5: out_tok = attn @ v_tok (unchanged)
__global__ __launch_bounds__(256) void k5_av(
    const bf16* __restrict__ tok, const float* __restrict__ attn, bf16* __restrict__ otok){
  int t = threadIdx.x;
  u32 bid = blockIdx.x;
  u32 io = bid & 7u, h = (bid >> 3) & 7u, b = bid >> 6;
  const bf16* vb = tok + ((size_t)(((2 * 16 + b) * 8 + h) * 64)) * 8192;
  const float* ab = attn + (((size_t)b * 8 + h) * 64 + io * 8) * 64;
  bf16* ob = otok + ((((size_t)b * 8 + h) * 64 + io * 8)) * 8192;

  for (int g = 0; g < 4; g++){
    int d = g * 2048 + t * 8;
    float acc[8][8];
    #pragma unroll
    for (int ii = 0; ii < 8; ii++)
      #pragma unroll
      for (int u = 0; u < 8; u++) acc[ii][u] = 0.f;
    for (int j = 0; j < 64; j++){
      uint4 vv = *(const uint4*)(vb + (size_t)j * 8192 + d);
      float vf[8];
      unpack8(vv, vf);
      #pragma unroll
      for (int ii = 0; ii < 8; ii++){
        float a = ab[ii * 64 + j];
        #pragma unroll
        for (int u = 0; u < 8; u++) acc[ii][u] += a * vf[u];
      }
    }
    #pragma unroll
    for (int ii = 0; ii < 8; ii++){
      uint4 w;
      w.x = f2bbits(acc[ii][0]) | (f2bbits(acc[ii][1]) << 16);
      w.y = f2bbits(acc[ii][2]) | (f2bbits(acc[ii][3]) << 16);
      w.z = f2bbits(acc[ii][4]) | (f2bbits(acc[ii][5]) << 16);
      w.w = f2bbits(acc[ii][6]) | (f2bbits(acc[ii][7]) << 16);
      *(uint4*)(ob + (size_t)ii * 8192 + d) = w;
    }
  }
}

// ---------------- K6 (MFMA): out[b,64,HW] fp32 = Wp[64,64] x OT[64,HW] + bias
__global__ __launch_bounds__(256) void k6_mfma(
    const bf16* __restrict__ otok, const float* __restrict__ wp,
    const float* __restrict__ bp, float* __restrict__ out){
  __shared__ uint4 xs[1024];
  int t = threadIdx.x;
  int lane = t & 63, w = t >> 6;
  u32 pix0 = blockIdx.x * 128u;
  u32 b = pix0 >> 16, hw0 = pix0 & 65535u;
  int y = (int)(hw0 >> 8);                  // constant per block
  int p0 = y & 31, h = p0 >> 2, prow = (p0 & 3) * 2048;
  int iy = (y >> 5) << 3;

  { // stage gathered otok rows: [c8][pix][j]
    int pix = t & 127, half = t >> 7;
    int xx = (int)(hw0 & 255u) + pix;
    int i = iy + (xx >> 5), p1 = xx & 31;
    const bf16* ip = otok + ((((size_t)b * 8 + h) * 64 + i)) * 8192 + prow + p1 * 64;
    #pragma unroll
    for (int g = 0; g < 4; g++){
      int c8 = half * 4 + g;
      xs[c8 * 128 + pix] = *(const uint4*)(ip + c8 * 8);
    }
  }

  int r16 = lane & 15, g4 = lane >> 4;
  bf16x8 af[2];
  int och = w * 16 + r16;
  #pragma unroll
  for (int kt = 0; kt < 2; kt++){
    const float* wr = wp + och * 64 + kt * 32 + g4 * 8;
    ABu pk;
    #pragma unroll
    for (int j = 0; j < 4; j++)
      pk.u[j] = f2bbits(wr[2 * j]) | (f2bbits(wr[2 * j + 1]) << 16);
    af[kt] = pk.v;
  }
  float bias[4];
  #pragma unroll
  for (int r = 0; r < 4; r++) bias[r] = bp[w * 16 + g4 * 4 + r];
  __syncthreads();

  f32x4 acc[8];
  #pragma unroll
  for (int pt = 0; pt < 8; pt++) acc[pt] = (f32x4){bias[0], bias[1], bias[2], bias[3]};

  #pragma unroll
  for (int pt = 0; pt < 8; pt++){
    uint4 u0 = xs[(0 * 4 + g4) * 128 + pt * 16 + r16];
    uint4 u1 = xs[(1 * 4 + g4) * 128 + pt * 16 + r16];
    bf16x8 b0 = *reinterpret_cast<bf16x8*>(&u0);
    bf16x8 b1 = *reinterpret_cast<bf16x8*>(&u1);
    acc[pt] = __builtin_amdgcn_mfma_f32_16x16x32_bf16(af[0], b0, acc[pt], 0, 0, 0);
    acc[pt] = __builtin_amdgcn_mfma_f32_16x16x32_bf16(af[1], b1, acc[pt], 0, 0, 0);
  }

  float* op = out + (size_t)b * 64 * HWSZ + hw0;
  int ochb = w * 16 + g4 * 4;
  #pragma unroll
  for (int pt = 0; pt < 8; pt++)
    #pragma unroll
    for (int r = 0; r < 4; r++)
      op[(size_t)(ochb + r) * HWSZ + pt * 16 + r16] = acc[pt][r];
}

extern "C" void kernel_launch(void* const* d_in, const int* in_sizes, int n_in,
                              void* d_out, int out_size, void* d_ws, size_t ws_size,
                              hipStream_t stream){
  const float* x   = (const float*)d_in[0];
  const float* wq  = (const float*)d_in[1];
  const float* wdw = (const float*)d_in[2];
  const float* wp  = (const float*)d_in[3];
  const float* bp  = (const float*)d_in[4];
  const float* pos = (const float*)d_in[5];
  float* out = (float*)d_out;
  (void)in_sizes; (void)n_in; (void)out_size; (void)ws_size;

  char* ws = (char*)d_ws;
  bf16*  qkv1 = (bf16*)ws;
  bf16*  tok  = (bf16*)(ws + 402653184u);
  bf16*  otok = (bf16*)ws;                  // region A reuse after K2
  float* sim4 = (float*)(ws + 134217728u);
  float* attn = (float*)(ws + 142606336u);

  k1_mfma<<<dim3(8192),  dim3(256), 0, stream>>>(x, wq, qkv1);
  k2_dwconv_tok<<<dim3(24576), dim3(256), 0, stream>>>(qkv1, wdw, tok);
  k3_sim<<<dim3(512),   dim3(256), 0, stream>>>(tok, sim4);
  k4_softmax<<<dim3(8192), dim3(64), 0, stream>>>(sim4, pos, attn);
  k5_av<<<dim3(1024),  dim3(256), 0, stream>>>(tok, attn, otok);
  k6_mfma<<<dim3(8192), dim3(256), 0, stream>>>(otok, wp, bp, out);
}

// Round 3
// 990.107 us; speedup vs baseline: 1.9851x; 1.3119x over previous
//
#include <hip/hip_runtime.h>
#include <hip/hip_bf16.h>

typedef __hip_bfloat16 bf16;
typedef unsigned int u32;
typedef __attribute__((ext_vector_type(8))) short bf16x8;
typedef __attribute__((ext_vector_type(4))) float f32x4;

#define HWSZ 65536u   // 256*256

__device__ __forceinline__ float b2f_lo(u32 w){ return __uint_as_float(w << 16); }
__device__ __forceinline__ float b2f_hi(u32 w){ return __uint_as_float(w & 0xffff0000u); }
__device__ __forceinline__ float b2f(bf16 v){ return __bfloat162float(v); }
__device__ __forceinline__ bf16 f2b(float v){ return __float2bfloat16(v); }

__device__ __forceinline__ u32 f2bbits(float f){
  u32 x = __float_as_uint(f);
  return ((x + 0x7fffu + ((x >> 16) & 1u)) >> 16) & 0xffffu;  // RNE
}

__device__ __forceinline__ void unpack8(uint4 v, float* f){
  f[0]=b2f_lo(v.x); f[1]=b2f_hi(v.x);
  f[2]=b2f_lo(v.y); f[3]=b2f_hi(v.y);
  f[4]=b2f_lo(v.z); f[5]=b2f_hi(v.z);
  f[6]=b2f_lo(v.w); f[7]=b2f_hi(v.w);
}

union ABu { u32 u[4]; bf16x8 v; uint4 q; };

// ---------------- K1 (MFMA): qkv1[b,192,HW] bf16 = W[192,64] x X[64,HW]
__global__ __launch_bounds__(256) void k1_mfma(
    const float* __restrict__ x, const float* __restrict__ wq, bf16* __restrict__ qkv1){
  __shared__ uint4 xs[1024];                 // 8 c8-groups * 128 pix
  int t = threadIdx.x;
  int lane = t & 63, w = t >> 6;
  u32 pix0 = blockIdx.x * 128u;
  u32 b = pix0 >> 16, hw0 = pix0 & 65535u;

  { // stage X: fp32 -> bf16, [c8][pix][j]
    int pix = t & 127, half = t >> 7;
    const float* xp = x + (size_t)b * 64 * HWSZ + hw0 + pix;
    #pragma unroll
    for (int g = 0; g < 4; g++){
      int c8 = half * 4 + g;
      ABu pk;
      #pragma unroll
      for (int j = 0; j < 4; j++){
        float f0 = xp[(size_t)(c8 * 8 + 2 * j)     * HWSZ];
        float f1 = xp[(size_t)(c8 * 8 + 2 * j + 1) * HWSZ];
        pk.u[j] = f2bbits(f0) | (f2bbits(f1) << 16);
      }
      xs[c8 * 128 + pix] = pk.q;
    }
  }

  int r16 = lane & 15, g4 = lane >> 4;
  bf16x8 af[3][2];
  #pragma unroll
  for (int ot = 0; ot < 3; ot++){
    int och = (w * 3 + ot) * 16 + r16;
    #pragma unroll
    for (int kt = 0; kt < 2; kt++){
      const float* wr = wq + och * 64 + kt * 32 + g4 * 8;
      ABu pk;
      #pragma unroll
      for (int j = 0; j < 4; j++)
        pk.u[j] = f2bbits(wr[2 * j]) | (f2bbits(wr[2 * j + 1]) << 16);
      af[ot][kt] = pk.v;
    }
  }
  __syncthreads();

  f32x4 acc[3][8];
  #pragma unroll
  for (int ot = 0; ot < 3; ot++)
    #pragma unroll
    for (int pt = 0; pt < 8; pt++) acc[ot][pt] = (f32x4){0.f,0.f,0.f,0.f};

  #pragma unroll
  for (int pt = 0; pt < 8; pt++){
    uint4 u0 = xs[(0 * 4 + g4) * 128 + pt * 16 + r16];
    uint4 u1 = xs[(1 * 4 + g4) * 128 + pt * 16 + r16];
    bf16x8 b0 = *reinterpret_cast<bf16x8*>(&u0);
    bf16x8 b1 = *reinterpret_cast<bf16x8*>(&u1);
    #pragma unroll
    for (int ot = 0; ot < 3; ot++){
      acc[ot][pt] = __builtin_amdgcn_mfma_f32_16x16x32_bf16(af[ot][0], b0, acc[ot][pt], 0, 0, 0);
      acc[ot][pt] = __builtin_amdgcn_mfma_f32_16x16x32_bf16(af[ot][1], b1, acc[ot][pt], 0, 0, 0);
    }
  }

  bf16* op = qkv1 + (size_t)b * 192 * HWSZ + hw0;
  #pragma unroll
  for (int ot = 0; ot < 3; ot++){
    int ochb = (w * 3 + ot) * 16 + g4 * 4;
    #pragma unroll
    for (int pt = 0; pt < 8; pt++)
      #pragma unroll
      for (int r = 0; r < 4; r++)
        op[(size_t)(ochb + r) * HWSZ + pt * 16 + r16] = f2b(acc[ot][pt][r]);
  }
}

// ---------------- K2' : 3x3 depthwise conv + tokenize, LDS-free, register-streamed
// block = (b,g,win); thread = (ch-pair c2, row-quad rq). 2ch x 4rows x 32cols per thread.
__device__ __forceinline__ void ldrow(const bf16* __restrict__ src, int y, int cb, uint4* d){
  if ((u32)y < 256u){
    const bf16* p = src + (y << 8);
    #pragma unroll
    for (int u = 0; u < 4; u++){
      int c = cb + 8 * u;
      if ((u32)c < 256u) d[u] = *(const uint4*)(p + c);
      else               d[u] = make_uint4(0u,0u,0u,0u);
    }
  } else {
    #pragma unroll
    for (int u = 0; u < 4; u++) d[u] = make_uint4(0u,0u,0u,0u);
  }
}

__device__ __forceinline__ float extc(const uint4* b4, int e){
  const u32* wv = (const u32*)b4;
  u32 x = wv[e >> 1];
  return (e & 1) ? b2f_hi(x) : b2f_lo(x);
}

__global__ __launch_bounds__(256) void k2_dwconv_tok(
    const bf16* __restrict__ qkv1, const float* __restrict__ wdw, u32* __restrict__ tok){
  int t = threadIdx.x;
  u32 n = blockIdx.x;
  u32 bid = (n & 7u) * 384u + (n >> 3);     // XCD swizzle (3072 = 8*384, bijective)
  u32 win = bid & 63u, g = (bid >> 6) % 3u, b = bid / 192u;
  u32 wy = win >> 3, wx = win & 7u;
  int c2 = t & 31, rq = t >> 5;             // rq == head h
  int ch0 = 2 * c2;
  int y0 = (int)(wy * 32u) + rq * 4;        // first output row (global)
  int x0 = (int)(wx * 32u);

  const float* wp0 = wdw + (size_t)g * 576 + ch0 * 9;
  float w0[9], w1[9];
  #pragma unroll
  for (int k = 0; k < 9; k++){ w0[k] = wp0[k]; w1[k] = wp0[9 + k]; }

  const bf16* src0 = qkv1 + ((size_t)b * 192 + g * 64 + ch0) * HWSZ;
  const bf16* src1 = src0 + HWSZ;
  // tok element base (in bf16 elems): [g][b][h=rq][win][d]; d = rr*2048 + p1*64 + ch
  size_t obase = (((((size_t)g * 16 + b) * 8 + rq) * 64 + win) * 8192) + (size_t)ch0;

  #pragma unroll
  for (int k = 0; k < 2; k++){              // two 16-col chunks
    int cb = x0 + 16 * k - 8;               // buffer covers cols [cb, cb+32)
    uint4 buf[2][3][4];
    ldrow(src0, y0 - 1, cb, buf[0][0]); ldrow(src1, y0 - 1, cb, buf[1][0]);
    ldrow(src0, y0,     cb, buf[0][1]); ldrow(src1, y0,     cb, buf[1][1]);
    ldrow(src0, y0 + 1, cb, buf[0][2]); ldrow(src1, y0 + 1, cb, buf[1][2]);

    #pragma unroll
    for (int rr = 0; rr < 4; rr++){
      const int sT = rr % 3, sM = (rr + 1) % 3, sB = (rr + 2) % 3;
      // rolling 3-col windows, both channels
      float l0T = extc(buf[0][sT], 7), m0T = extc(buf[0][sT], 8);
      float l0M = extc(buf[0][sM], 7), m0M = extc(buf[0][sM], 8);
      float l0B = extc(buf[0][sB], 7), m0B = extc(buf[0][sB], 8);
      float l1T = extc(buf[1][sT], 7), m1T = extc(buf[1][sT], 8);
      float l1M = extc(buf[1][sM], 7), m1M = extc(buf[1][sM], 8);
      float l1B = extc(buf[1][sB], 7), m1B = extc(buf[1][sB], 8);
      #pragma unroll
      for (int cc = 0; cc < 16; cc++){
        float r0T = extc(buf[0][sT], cc + 9);
        float r0M = extc(buf[0][sM], cc + 9);
        float r0B = extc(buf[0][sB], cc + 9);
        float r1T = extc(buf[1][sT], cc + 9);
        float r1M = extc(buf[1][sM], cc + 9);
        float r1B = extc(buf[1][sB], cc + 9);
        float a0 = l0T*w0[0] + m0T*w0[1] + r0T*w0[2]
                 + l0M*w0[3] + m0M*w0[4] + r0M*w0[5]
                 + l0B*w0[6] + m0B*w0[7] + r0B*w0[8];
        float a1 = l1T*w1[0] + m1T*w1[1] + r1T*w1[2]
                 + l1M*w1[3] + m1M*w1[4] + r1M*w1[5]
                 + l1B*w1[6] + m1B*w1[7] + r1B*w1[8];
        int p1 = k * 16 + cc;
        tok[(obase + (size_t)rr * 2048 + (size_t)p1 * 64) >> 1] =
            f2bbits(a0) | (f2bbits(a1) << 16);
        l0T = m0T; m0T = r0T; l0M = m0M; m0M = r0M; l0B = m0B; m0B = r0B;
        l1T = m1T; m1T = r1T; l1M = m1M; m1M = r1M; l1B = m1B; m1B = r1B;
      }
      if (rr < 3){  // slide: overwrite oldest slot with row y0+rr+2
        ldrow(src0, y0 + rr + 2, cb, buf[0][sT]);
        ldrow(src1, y0 + rr + 2, cb, buf[1][sT]);
      }
    }
  }
}

// ---------------- K3: sim partials (unchanged fp32)
__global__ __launch_bounds__(256) void k3_sim(
    const bf16* __restrict__ tok, float* __restrict__ sim4){
  int t = threadIdx.x;
  u32 bid = blockIdx.x;
  u32 part = bid & 3u, h = (bid >> 2) & 7u, b = bid >> 5;
  int ti = t & 15, tj = t >> 4;
  const bf16* qb = tok + ((size_t)(((0 * 16 + b) * 8 + h) * 64)) * 8192;
  const bf16* kb = tok + ((size_t)(((1 * 16 + b) * 8 + h) * 64)) * 8192;

  __shared__ float qc[64 * 68];
  __shared__ float kc[64 * 68];
  float acc[4][4] = {{0.f}};

  for (int cc = 0; cc < 32; cc++){
    int d0 = part * 2048 + cc * 64;
    __syncthreads();
    #pragma unroll
    for (int rr = 0; rr < 2; rr++){
      int lin = (rr * 256 + t) * 8;
      int i = lin >> 6, dd = lin & 63;
      uint4 qv = *(const uint4*)(qb + (size_t)i * 8192 + d0 + dd);
      uint4 kv = *(const uint4*)(kb + (size_t)i * 8192 + d0 + dd);
      float qf[8], kf[8];
      unpack8(qv, qf); unpack8(kv, kf);
      #pragma unroll
      for (int u = 0; u < 8; u++){
        qc[(dd + u) * 68 + i] = qf[u];
        kc[(dd + u) * 68 + i] = kf[u];
      }
    }
    __syncthreads();
    for (int dd = 0; dd < 64; dd++){
      float4 qv = *(const float4*)&qc[dd * 68 + ti * 4];
      float4 kv = *(const float4*)&kc[dd * 68 + tj * 4];
      acc[0][0] += qv.x * kv.x; acc[0][1] += qv.x * kv.y; acc[0][2] += qv.x * kv.z; acc[0][3] += qv.x * kv.w;
      acc[1][0] += qv.y * kv.x; acc[1][1] += qv.y * kv.y; acc[1][2] += qv.y * kv.z; acc[1][3] += qv.y * kv.w;
      acc[2][0] += qv.z * kv.x; acc[2][1] += qv.z * kv.y; acc[2][2] += qv.z * kv.z; acc[2][3] += qv.z * kv.w;
      acc[3][0] += qv.w * kv.x; acc[3][1] += qv.w * kv.y; acc[3][2] += qv.w * kv.z; acc[3][3] += qv.w * kv.w;
    }
  }
  float* sp = sim4 + ((((size_t)part * 16 + b) * 8 + h) * 64) * 64;
  #pragma unroll
  for (int ii = 0; ii < 4; ii++)
    #pragma unroll
    for (int jj = 0; jj < 4; jj++)
      sp[(ti * 4 + ii) * 64 + (tj * 4 + jj)] = acc[ii][jj];
}

// ---------------- K4: softmax (unchanged)
__global__ __launch_bounds__(64) void k4_softmax(
    const float* __restrict__ sim4, const float* __restrict__ pos, float* __restrict__ attn){
  int j = threadIdx.x;
  u32 bid = blockIdx.x;
  u32 i = bid & 63u, h = (bid >> 6) & 7u, b = bid >> 9;
  size_t o = (((size_t)b * 8 + h) * 64 + i) * 64 + j;
  const size_t pstride = (size_t)16 * 8 * 64 * 64;
  float s = sim4[o] + sim4[o + pstride] + sim4[o + 2 * pstride] + sim4[o + 3 * pstride];
  s = s * 0.011048543456039806f + pos[(((size_t)h * 64) + i) * 64 + j];
  float m = s;
  #pragma unroll
  for (int off = 32; off; off >>= 1) m = fmaxf(m, __shfl_xor(m, off));
  float e = __expf(s - m);
  float sum = e;
  #pragma unroll
  for (int off = 32; off; off >>= 1) sum += __shfl_xor(sum, off);
  attn[o] = e / sum;
}

// ---------------- K5: out_tok = attn @ v_tok (unchanged)
__global__ __launch_bounds__(256) void k5_av(
    const bf16* __restrict__ tok, const float* __restrict__ attn, bf16* __restrict__ otok){
  int t = threadIdx.x;
  u32 bid = blockIdx.x;
  u32 io = bid & 7u, h = (bid >> 3) & 7u, b = bid >> 6;
  const bf16* vb = tok + ((size_t)(((2 * 16 + b) * 8 + h) * 64)) * 8192;
  const float* ab = attn + (((size_t)b * 8 + h) * 64 + io * 8) * 64;
  bf16* ob = otok + ((((size_t)b * 8 + h) * 64 + io * 8)) * 8192;

  for (int g = 0; g < 4; g++){
    int d = g * 2048 + t * 8;
    float acc[8][8];
    #pragma unroll
    for (int ii = 0; ii < 8; ii++)
      #pragma unroll
      for (int u = 0; u < 8; u++) acc[ii][u] = 0.f;
    for (int j = 0; j < 64; j++){
      uint4 vv = *(const uint4*)(vb + (size_t)j * 8192 + d);
      float vf[8];
      unpack8(vv, vf);
      #pragma unroll
      for (int ii = 0; ii < 8; ii++){
        float a = ab[ii * 64 + j];
        #pragma unroll
        for (int u = 0; u < 8; u++) acc[ii][u] += a * vf[u];
      }
    }
    #pragma unroll
    for (int ii = 0; ii < 8; ii++){
      uint4 w;
      w.x = f2bbits(acc[ii][0]) | (f2bbits(acc[ii][1]) << 16);
      w.y = f2bbits(acc[ii][2]) | (f2bbits(acc[ii][3]) << 16);
      w.z = f2bbits(acc[ii][4]) | (f2bbits(acc[ii][5]) << 16);
      w.w = f2bbits(acc[ii][6]) | (f2bbits(acc[ii][7]) << 16);
      *(uint4*)(ob + (size_t)ii * 8192 + d) = w;
    }
  }
}

// ---------------- K6 (MFMA): out[b,64,HW] fp32 = Wp[64,64] x OT[64,HW] + bias
__global__ __launch_bounds__(256) void k6_mfma(
    const bf16* __restrict__ otok, const float* __restrict__ wp,
    const float* __restrict__ bp, float* __restrict__ out){
  __shared__ uint4 xs[1024];
  int t = threadIdx.x;
  int lane = t & 63, w = t >> 6;
  u32 pix0 = blockIdx.x * 128u;
  u32 b = pix0 >> 16, hw0 = pix0 & 65535u;
  int y = (int)(hw0 >> 8);
  int p0 = y & 31, h = p0 >> 2, prow = (p0 & 3) * 2048;
  int iy = (y >> 5) << 3;

  {
    int pix = t & 127, half = t >> 7;
    int xx = (int)(hw0 & 255u) + pix;
    int i = iy + (xx >> 5), p1 = xx & 31;
    const bf16* ip = otok + ((((size_t)b * 8 + h) * 64 + i)) * 8192 + prow + p1 * 64;
    #pragma unroll
    for (int g = 0; g < 4; g++){
      int c8 = half * 4 + g;
      xs[c8 * 128 + pix] = *(const uint4*)(ip + c8 * 8);
    }
  }

  int r16 = lane & 15, g4 = lane >> 4;
  bf16x8 af[2];
  int och = w * 16 + r16;
  #pragma unroll
  for (int kt = 0; kt < 2; kt++){
    const float* wr = wp + och * 64 + kt * 32 + g4 * 8;
    ABu pk;
    #pragma unroll
    for (int j = 0; j < 4; j++)
      pk.u[j] = f2bbits(wr[2 * j]) | (f2bbits(wr[2 * j + 1]) << 16);
    af[kt] = pk.v;
  }
  float bias[4];
  #pragma unroll
  for (int r = 0; r < 4; r++) bias[r] = bp[w * 16 + g4 * 4 + r];
  __syncthreads();

  f32x4 acc[8];
  #pragma unroll
  for (int pt = 0; pt < 8; pt++) acc[pt] = (f32x4){bias[0], bias[1], bias[2], bias[3]};

  #pragma unroll
  for (int pt = 0; pt < 8; pt++){
    uint4 u0 = xs[(0 * 4 + g4) * 128 + pt * 16 + r16];
    uint4 u1 = xs[(1 * 4 + g4) * 128 + pt * 16 + r16];
    bf16x8 b0 = *reinterpret_cast<bf16x8*>(&u0);
    bf16x8 b1 = *reinterpret_cast<bf16x8*>(&u1);
    acc[pt] = __builtin_amdgcn_mfma_f32_16x16x32_bf16(af[0], b0, acc[pt], 0, 0, 0);
    acc[pt] = __builtin_amdgcn_mfma_f32_16x16x32_bf16(af[1], b1, acc[pt], 0, 0, 0);
  }

  float* op = out + (size_t)b * 64 * HWSZ + hw0;
  int ochb = w * 16 + g4 * 4;
  #pragma unroll
  for (int pt = 0; pt < 8; pt++)
    #pragma unroll
    for (int r = 0; r < 4; r++)
      op[(size_t)(ochb + r) * HWSZ + pt * 16 + r16] = acc[pt][r];
}

extern "C" void kernel_launch(void* const* d_in, const int* in_sizes, int n_in,
                              void* d_out, int out_size, void* d_ws, size_t ws_size,
                              hipStream_t stream){
  const float* x   = (const float*)d_in[0];
  const float* wq  = (const float*)d_in[1];
  const float* wdw = (const float*)d_in[2];
  const float* wp  = (const float*)d_in[3];
  const float* bp  = (const float*)d_in[4];
  const float* pos = (const float*)d_in[5];
  float* out = (float*)d_out;
  (void)in_sizes; (void)n_in; (void)out_size; (void)ws_size;

  char* ws = (char*)d_ws;
  bf16*  qkv1 = (bf16*)ws;
  bf16*  tok  = (bf16*)(ws + 402653184u);
  bf16*  otok = (bf16*)ws;                  // region A reuse after K2
  float* sim4 = (float*)(ws + 134217728u);
  float* attn = (float*)(ws + 142606336u);

  k1_mfma<<<dim3(8192),  dim3(256), 0, stream>>>(x, wq, qkv1);
  k2_dwconv_tok<<<dim3(3072), dim3(256), 0, stream>>>(qkv1, wdw, (u32*)tok);
  k3_sim<<<dim3(512),   dim3(256), 0, stream>>>(tok, sim4);
  k4_softmax<<<dim3(8192), dim3(64), 0, stream>>>(sim4, pos, attn);
  k5_av<<<dim3(1024),  dim3(256), 0, stream>>>(tok, attn, otok);
  k6_mfma<<<dim3(8192), dim3(256), 0, stream>>>(otok, wp, bp, out);
}

// Round 4
// 853.071 us; speedup vs baseline: 2.3040x; 1.1606x over previous
//
#include <hip/hip_runtime.h>
#include <hip/hip_bf16.h>

typedef __hip_bfloat16 bf16;
typedef unsigned int u32;
typedef __attribute__((ext_vector_type(8))) short bf16x8;
typedef __attribute__((ext_vector_type(4))) float f32x4;

#define HWSZ 65536u   // 256*256

__device__ __forceinline__ float b2f_lo(u32 w){ return __uint_as_float(w << 16); }
__device__ __forceinline__ float b2f_hi(u32 w){ return __uint_as_float(w & 0xffff0000u); }
__device__ __forceinline__ float b2f(bf16 v){ return __bfloat162float(v); }
__device__ __forceinline__ bf16 f2b(float v){ return __float2bfloat16(v); }

__device__ __forceinline__ u32 f2bbits(float f){
  u32 x = __float_as_uint(f);
  return ((x + 0x7fffu + ((x >> 16) & 1u)) >> 16) & 0xffffu;  // RNE
}

__device__ __forceinline__ void unpack8(uint4 v, float* f){
  f[0]=b2f_lo(v.x); f[1]=b2f_hi(v.x);
  f[2]=b2f_lo(v.y); f[3]=b2f_hi(v.y);
  f[4]=b2f_lo(v.z); f[5]=b2f_hi(v.z);
  f[6]=b2f_lo(v.w); f[7]=b2f_hi(v.w);
}

union ABu { u32 u[4]; bf16x8 v; uint4 q; };

// ---------------- K1 (MFMA): qkv1[b,192,HW] bf16 = W[192,64] x X[64,HW]
__global__ __launch_bounds__(256) void k1_mfma(
    const float* __restrict__ x, const float* __restrict__ wq, bf16* __restrict__ qkv1){
  __shared__ uint4 xs[1024];                 // 8 c8-groups * 128 pix
  int t = threadIdx.x;
  int lane = t & 63, w = t >> 6;
  u32 pix0 = blockIdx.x * 128u;
  u32 b = pix0 >> 16, hw0 = pix0 & 65535u;

  { // stage X: fp32 -> bf16, [c8][pix][j]
    int pix = t & 127, half = t >> 7;
    const float* xp = x + (size_t)b * 64 * HWSZ + hw0 + pix;
    #pragma unroll
    for (int g = 0; g < 4; g++){
      int c8 = half * 4 + g;
      ABu pk;
      #pragma unroll
      for (int j = 0; j < 4; j++){
        float f0 = xp[(size_t)(c8 * 8 + 2 * j)     * HWSZ];
        float f1 = xp[(size_t)(c8 * 8 + 2 * j + 1) * HWSZ];
        pk.u[j] = f2bbits(f0) | (f2bbits(f1) << 16);
      }
      xs[c8 * 128 + pix] = pk.q;
    }
  }

  int r16 = lane & 15, g4 = lane >> 4;
  bf16x8 af[3][2];
  #pragma unroll
  for (int ot = 0; ot < 3; ot++){
    int och = (w * 3 + ot) * 16 + r16;
    #pragma unroll
    for (int kt = 0; kt < 2; kt++){
      const float* wr = wq + och * 64 + kt * 32 + g4 * 8;
      ABu pk;
      #pragma unroll
      for (int j = 0; j < 4; j++)
        pk.u[j] = f2bbits(wr[2 * j]) | (f2bbits(wr[2 * j + 1]) << 16);
      af[ot][kt] = pk.v;
    }
  }
  __syncthreads();

  f32x4 acc[3][8];
  #pragma unroll
  for (int ot = 0; ot < 3; ot++)
    #pragma unroll
    for (int pt = 0; pt < 8; pt++) acc[ot][pt] = (f32x4){0.f,0.f,0.f,0.f};

  #pragma unroll
  for (int pt = 0; pt < 8; pt++){
    uint4 u0 = xs[(0 * 4 + g4) * 128 + pt * 16 + r16];
    uint4 u1 = xs[(1 * 4 + g4) * 128 + pt * 16 + r16];
    bf16x8 b0 = *reinterpret_cast<bf16x8*>(&u0);
    bf16x8 b1 = *reinterpret_cast<bf16x8*>(&u1);
    #pragma unroll
    for (int ot = 0; ot < 3; ot++){
      acc[ot][pt] = __builtin_amdgcn_mfma_f32_16x16x32_bf16(af[ot][0], b0, acc[ot][pt], 0, 0, 0);
      acc[ot][pt] = __builtin_amdgcn_mfma_f32_16x16x32_bf16(af[ot][1], b1, acc[ot][pt], 0, 0, 0);
    }
  }

  bf16* op = qkv1 + (size_t)b * 192 * HWSZ + hw0;
  #pragma unroll
  for (int ot = 0; ot < 3; ot++){
    int ochb = (w * 3 + ot) * 16 + g4 * 4;
    #pragma unroll
    for (int pt = 0; pt < 8; pt++)
      #pragma unroll
      for (int r = 0; r < 4; r++)
        op[(size_t)(ochb + r) * HWSZ + pt * 16 + r16] = f2b(acc[ot][pt][r]);
  }
}

// ---------------- K2 (v4): 3x3 depthwise conv + tokenize, full-line reads
// block = (b, g, 16-row band yb, 64-col pair wx2); thread = (ch c, row-quad rq).
// Each lane reads full 128B lines (8 x uint4); writes 64-lane-coalesced tok lines.
__global__ __launch_bounds__(256) void k2_dwconv_tok(
    const bf16* __restrict__ qkv1, const float* __restrict__ wdw, bf16* __restrict__ tok){
  int t = threadIdx.x;
  u32 n = blockIdx.x;
  u32 bid = (n & 7u) * 384u + (n >> 3);     // XCD swizzle (3072 = 8*384, bijective)
  u32 wx2 = bid & 3u, yb = (bid >> 2) & 15u, g = (bid >> 6) % 3u, b = bid / 192u;
  int c = t & 63, rq = t >> 6;              // 64 ch x 4 row-quads
  int y0 = (int)(yb * 16u) + rq * 4;
  int x0 = (int)(wx2 * 64u);

  const float* wp = wdw + ((size_t)g * 64 + c) * 9;
  float w0=wp[0],w1=wp[1],w2=wp[2],w3=wp[3],w4=wp[4],w5=wp[5],w6=wp[6],w7=wp[7],w8=wp[8];

  const bf16* src = qkv1 + ((size_t)b * 192 + g * 64 + c) * HWSZ;

  // per-thread constant output base (elements)
  int h = 4 * (int)(yb & 1u) + rq;
  size_t base = ((((((size_t)g * 16 + b) * 8 + h) * 64)
                + (size_t)(yb >> 1) * 8 + wx2 * 2) * 8192) + (size_t)c;
  bf16* op = tok + base;

  // rolling 3-row buffers: 8 uint4 center (64 cols) + L/R halo floats
  uint4 rb[3][8];
  float Lh[3], Rh[3];

  #define LDROW(s, yy) do{                                            \
    int _y = (yy);                                                    \
    if ((u32)_y < 256u){                                              \
      const bf16* _p = src + (_y << 8) + x0;                          \
      _Pragma("unroll")                                               \
      for (int _j = 0; _j < 8; _j++) rb[s][_j] = *(const uint4*)(_p + _j * 8); \
      Lh[s] = (x0 > 0)        ? b2f(_p[-1]) : 0.f;                    \
      Rh[s] = (x0 + 64 < 256) ? b2f(_p[64]) : 0.f;                    \
    } else {                                                          \
      _Pragma("unroll")                                               \
      for (int _j = 0; _j < 8; _j++) rb[s][_j] = make_uint4(0u,0u,0u,0u); \
      Lh[s] = 0.f; Rh[s] = 0.f;                                       \
    }                                                                 \
  }while(0)

  LDROW(0, y0 - 1);
  LDROW(1, y0);
  LDROW(2, y0 + 1);

  #pragma unroll
  for (int rr = 0; rr < 4; rr++){
    const int sT = rr % 3, sM = (rr + 1) % 3, sB = (rr + 2) % 3;
    const u32* uT = (const u32*)rb[sT];
    const u32* uM = (const u32*)rb[sM];
    const u32* uB = (const u32*)rb[sB];
    float lT = Lh[sT], mT = b2f_lo(uT[0]);
    float lM = Lh[sM], mM = b2f_lo(uM[0]);
    float lB = Lh[sB], mB = b2f_lo(uB[0]);
    #pragma unroll
    for (int j = 0; j < 64; j++){
      float rT, rM, rB;
      if (j < 63){
        int e = j + 1;
        u32 xT = uT[e >> 1], xM = uM[e >> 1], xB = uB[e >> 1];
        if (e & 1){ rT = b2f_hi(xT); rM = b2f_hi(xM); rB = b2f_hi(xB); }
        else      { rT = b2f_lo(xT); rM = b2f_lo(xM); rB = b2f_lo(xB); }
      } else { rT = Rh[sT]; rM = Rh[sM]; rB = Rh[sB]; }
      float acc = lT*w0 + mT*w1 + rT*w2
                + lM*w3 + mM*w4 + rM*w5
                + lB*w6 + mB*w7 + rB*w8;
      op[(size_t)rr * 2048 + (j >> 5) * 8192 + (j & 31) * 64] = f2b(acc);
      lT = mT; mT = rT; lM = mM; mM = rM; lB = mB; mB = rB;
    }
    if (rr < 3){
      LDROW(sT, y0 + rr + 2);
    }
  }
  #undef LDROW
}

// ---------------- K3: sim partials (unchanged fp32)
__global__ __launch_bounds__(256) void k3_sim(
    const bf16* __restrict__ tok, float* __restrict__ sim4){
  int t = threadIdx.x;
  u32 bid = blockIdx.x;
  u32 part = bid & 3u, h = (bid >> 2) & 7u, b = bid >> 5;
  int ti = t & 15, tj = t >> 4;
  const bf16* qb = tok + ((size_t)(((0 * 16 + b) * 8 + h) * 64)) * 8192;
  const bf16* kb = tok + ((size_t)(((1 * 16 + b) * 8 + h) * 64)) * 8192;

  __shared__ float qc[64 * 68];
  __shared__ float kc[64 * 68];
  float acc[4][4] = {{0.f}};

  for (int cc = 0; cc < 32; cc++){
    int d0 = part * 2048 + cc * 64;
    __syncthreads();
    #pragma unroll
    for (int rr = 0; rr < 2; rr++){
      int lin = (rr * 256 + t) * 8;
      int i = lin >> 6, dd = lin & 63;
      uint4 qv = *(const uint4*)(qb + (size_t)i * 8192 + d0 + dd);
      uint4 kv = *(const uint4*)(kb + (size_t)i * 8192 + d0 + dd);
      float qf[8], kf[8];
      unpack8(qv, qf); unpack8(kv, kf);
      #pragma unroll
      for (int u = 0; u < 8; u++){
        qc[(dd + u) * 68 + i] = qf[u];
        kc[(dd + u) * 68 + i] = kf[u];
      }
    }
    __syncthreads();
    for (int dd = 0; dd < 64; dd++){
      float4 qv = *(const float4*)&qc[dd * 68 + ti * 4];
      float4 kv = *(const float4*)&kc[dd * 68 + tj * 4];
      acc[0][0] += qv.x * kv.x; acc[0][1] += qv.x * kv.y; acc[0][2] += qv.x * kv.z; acc[0][3] += qv.x * kv.w;
      acc[1][0] += qv.y * kv.x; acc[1][1] += qv.y * kv.y; acc[1][2] += qv.y * kv.z; acc[1][3] += qv.y * kv.w;
      acc[2][0] += qv.z * kv.x; acc[2][1] += qv.z * kv.y; acc[2][2] += qv.z * kv.z; acc[2][3] += qv.z * kv.w;
      acc[3][0] += qv.w * kv.x; acc[3][1] += qv.w * kv.y; acc[3][2] += qv.w * kv.z; acc[3][3] += qv.w * kv.w;
    }
  }
  float* sp = sim4 + ((((size_t)part * 16 + b) * 8 + h) * 64) * 64;
  #pragma unroll
  for (int ii = 0; ii < 4; ii++)
    #pragma unroll
    for (int jj = 0; jj < 4; jj++)
      sp[(ti * 4 + ii) * 64 + (tj * 4 + jj)] = acc[ii][jj];
}

// ---------------- K4: softmax (unchanged)
__global__ __launch_bounds__(64) void k4_softmax(
    const float* __restrict__ sim4, const float* __restrict__ pos, float* __restrict__ attn){
  int j = threadIdx.x;
  u32 bid = blockIdx.x;
  u32 i = bid & 63u, h = (bid >> 6) & 7u, b = bid >> 9;
  size_t o = (((size_t)b * 8 + h) * 64 + i) * 64 + j;
  const size_t pstride = (size_t)16 * 8 * 64 * 64;
  float s = sim4[o] + sim4[o + pstride] + sim4[o + 2 * pstride] + sim4[o + 3 * pstride];
  s = s * 0.011048543456039806f + pos[(((size_t)h * 64) + i) * 64 + j];
  float m = s;
  #pragma unroll
  for (int off = 32; off; off >>= 1) m = fmaxf(m, __shfl_xor(m, off));
  float e = __expf(s - m);
  float sum = e;
  #pragma unroll
  for (int off = 32; off; off >>= 1) sum += __shfl_xor(sum, off);
  attn[o] = e / sum;
}

// ---------------- K5: out_tok = attn @ v_tok (unchanged)
__global__ __launch_bounds__(256) void k5_av(
    const bf16* __restrict__ tok, const float* __restrict__ attn, bf16* __restrict__ otok){
  int t = threadIdx.x;
  u32 bid = blockIdx.x;
  u32 io = bid & 7u, h = (bid >> 3) & 7u, b = bid >> 6;
  const bf16* vb = tok + ((size_t)(((2 * 16 + b) * 8 + h) * 64)) * 8192;
  const float* ab = attn + (((size_t)b * 8 + h) * 64 + io * 8) * 64;
  bf16* ob = otok + ((((size_t)b * 8 + h) * 64 + io * 8)) * 8192;

  for (int g = 0; g < 4; g++){
    int d = g * 2048 + t * 8;
    float acc[8][8];
    #pragma unroll
    for (int ii = 0; ii < 8; ii++)
      #pragma unroll
      for (int u = 0; u < 8; u++) acc[ii][u] = 0.f;
    for (int j = 0; j < 64; j++){
      uint4 vv = *(const uint4*)(vb + (size_t)j * 8192 + d);
      float vf[8];
      unpack8(vv, vf);
      #pragma unroll
      for (int ii = 0; ii < 8; ii++){
        float a = ab[ii * 64 + j];
        #pragma unroll
        for (int u = 0; u < 8; u++) acc[ii][u] += a * vf[u];
      }
    }
    #pragma unroll
    for (int ii = 0; ii < 8; ii++){
      uint4 w;
      w.x = f2bbits(acc[ii][0]) | (f2bbits(acc[ii][1]) << 16);
      w.y = f2bbits(acc[ii][2]) | (f2bbits(acc[ii][3]) << 16);
      w.z = f2bbits(acc[ii][4]) | (f2bbits(acc[ii][5]) << 16);
      w.w = f2bbits(acc[ii][6]) | (f2bbits(acc[ii][7]) << 16);
      *(uint4*)(ob + (size_t)ii * 8192 + d) = w;
    }
  }
}

// ---------------- K6 (MFMA): out[b,64,HW] fp32 = Wp[64,64] x OT[64,HW] + bias
__global__ __launch_bounds__(256) void k6_mfma(
    const bf16* __restrict__ otok, const float* __restrict__ wp,
    const float* __restrict__ bp, float* __restrict__ out){
  __shared__ uint4 xs[1024];
  int t = threadIdx.x;
  int lane = t & 63, w = t >> 6;
  u32 pix0 = blockIdx.x * 128u;
  u32 b = pix0 >> 16, hw0 = pix0 & 65535u;
  int y = (int)(hw0 >> 8);
  int p0 = y & 31, h = p0 >> 2, prow = (p0 & 3) * 2048;
  int iy = (y >> 5) << 3;

  {
    int pix = t & 127, half = t >> 7;
    int xx = (int)(hw0 & 255u) + pix;
    int i = iy + (xx >> 5), p1 = xx & 31;
    const bf16* ip = otok + ((((size_t)b * 8 + h) * 64 + i)) * 8192 + prow + p1 * 64;
    #pragma unroll
    for (int g = 0; g < 4; g++){
      int c8 = half * 4 + g;
      xs[c8 * 128 + pix] = *(const uint4*)(ip + c8 * 8);
    }
  }

  int r16 = lane & 15, g4 = lane >> 4;
  bf16x8 af[2];
  int och = w * 16 + r16;
  #pragma unroll
  for (int kt = 0; kt < 2; kt++){
    const float* wr = wp + och * 64 + kt * 32 + g4 * 8;
    ABu pk;
    #pragma unroll
    for (int j = 0; j < 4; j++)
      pk.u[j] = f2bbits(wr[2 * j]) | (f2bbits(wr[2 * j + 1]) << 16);
    af[kt] = pk.v;
  }
  float bias[4];
  #pragma unroll
  for (int r = 0; r < 4; r++) bias[r] = bp[w * 16 + g4 * 4 + r];
  __syncthreads();

  f32x4 acc[8];
  #pragma unroll
  for (int pt = 0; pt < 8; pt++) acc[pt] = (f32x4){bias[0], bias[1], bias[2], bias[3]};

  #pragma unroll
  for (int pt = 0; pt < 8; pt++){
    uint4 u0 = xs[(0 * 4 + g4) * 128 + pt * 16 + r16];
    uint4 u1 = xs[(1 * 4 + g4) * 128 + pt * 16 + r16];
    bf16x8 b0 = *reinterpret_cast<bf16x8*>(&u0);
    bf16x8 b1 = *reinterpret_cast<bf16x8*>(&u1);
    acc[pt] = __builtin_amdgcn_mfma_f32_16x16x32_bf16(af[0], b0, acc[pt], 0, 0, 0);
    acc[pt] = __builtin_amdgcn_mfma_f32_16x16x32_bf16(af[1], b1, acc[pt], 0, 0, 0);
  }

  float* op = out + (size_t)b * 64 * HWSZ + hw0;
  int ochb = w * 16 + g4 * 4;
  #pragma unroll
  for (int pt = 0; pt < 8; pt++)
    #pragma unroll
    for (int r = 0; r < 4; r++)
      op[(size_t)(ochb + r) * HWSZ + pt * 16 + r16] = acc[pt][r];
}

extern "C" void kernel_launch(void* const* d_in, const int* in_sizes, int n_in,
                              void* d_out, int out_size, void* d_ws, size_t ws_size,
                              hipStream_t stream){
  const float* x   = (const float*)d_in[0];
  const float* wq  = (const float*)d_in[1];
  const float* wdw = (const float*)d_in[2];
  const float* wp  = (const float*)d_in[3];
  const float* bp  = (const float*)d_in[4];
  const float* pos = (const float*)d_in[5];
  float* out = (float*)d_out;
  (void)in_sizes; (void)n_in; (void)out_size; (void)ws_size;

  char* ws = (char*)d_ws;
  bf16*  qkv1 = (bf16*)ws;
  bf16*  tok  = (bf16*)(ws + 402653184u);
  bf16*  otok = (bf16*)ws;                  // region A reuse after K2
  float* sim4 = (float*)(ws + 134217728u);
  float* attn = (float*)(ws + 142606336u);

  k1_mfma<<<dim3(8192),  dim3(256), 0, stream>>>(x, wq, qkv1);
  k2_dwconv_tok<<<dim3(3072), dim3(256), 0, stream>>>(qkv1, wdw, tok);
  k3_sim<<<dim3(512),   dim3(256), 0, stream>>>(tok, sim4);
  k4_softmax<<<dim3(8192), dim3(64), 0, stream>>>(sim4, pos, attn);
  k5_av<<<dim3(1024),  dim3(256), 0, stream>>>(tok, attn, otok);
  k6_mfma<<<dim3(8192), dim3(256), 0, stream>>>(otok, wp, bp, out);
}

// Round 5
// 671.264 us; speedup vs baseline: 2.9281x; 1.2708x over previous
//
#include <hip/hip_runtime.h>
#include <hip/hip_bf16.h>

typedef __hip_bfloat16 bf16;
typedef unsigned int u32;
typedef __attribute__((ext_vector_type(8))) short bf16x8;
typedef __attribute__((ext_vector_type(4))) float f32x4;

#define HWSZ 65536u   // 256*256

__device__ __forceinline__ float b2f_lo(u32 w){ return __uint_as_float(w << 16); }
__device__ __forceinline__ float b2f_hi(u32 w){ return __uint_as_float(w & 0xffff0000u); }
__device__ __forceinline__ float b2f(bf16 v){ return __bfloat162float(v); }
__device__ __forceinline__ bf16 f2b(float v){ return __float2bfloat16(v); }

__device__ __forceinline__ u32 f2bbits(float f){
  u32 x = __float_as_uint(f);
  return ((x + 0x7fffu + ((x >> 16) & 1u)) >> 16) & 0xffffu;  // RNE
}

__device__ __forceinline__ void unpack8(uint4 v, float* f){
  f[0]=b2f_lo(v.x); f[1]=b2f_hi(v.x);
  f[2]=b2f_lo(v.y); f[3]=b2f_hi(v.y);
  f[4]=b2f_lo(v.z); f[5]=b2f_hi(v.z);
  f[6]=b2f_lo(v.w); f[7]=b2f_hi(v.w);
}

union ABu { u32 u[4]; bf16x8 v; uint4 q; };

// ---------------- K1 (MFMA): qkv1[b,192,HW] bf16 = W[192,64] x X[64,HW]
__global__ __launch_bounds__(256) void k1_mfma(
    const float* __restrict__ x, const float* __restrict__ wq, bf16* __restrict__ qkv1){
  __shared__ uint4 xs[1024];                 // 8 c8-groups * 128 pix
  int t = threadIdx.x;
  int lane = t & 63, w = t >> 6;
  u32 pix0 = blockIdx.x * 128u;
  u32 b = pix0 >> 16, hw0 = pix0 & 65535u;

  { // stage X: fp32 -> bf16, [c8][pix][j]
    int pix = t & 127, half = t >> 7;
    const float* xp = x + (size_t)b * 64 * HWSZ + hw0 + pix;
    #pragma unroll
    for (int g = 0; g < 4; g++){
      int c8 = half * 4 + g;
      ABu pk;
      #pragma unroll
      for (int j = 0; j < 4; j++){
        float f0 = xp[(size_t)(c8 * 8 + 2 * j)     * HWSZ];
        float f1 = xp[(size_t)(c8 * 8 + 2 * j + 1) * HWSZ];
        pk.u[j] = f2bbits(f0) | (f2bbits(f1) << 16);
      }
      xs[c8 * 128 + pix] = pk.q;
    }
  }

  int r16 = lane & 15, g4 = lane >> 4;
  bf16x8 af[3][2];
  #pragma unroll
  for (int ot = 0; ot < 3; ot++){
    int och = (w * 3 + ot) * 16 + r16;
    #pragma unroll
    for (int kt = 0; kt < 2; kt++){
      const float* wr = wq + och * 64 + kt * 32 + g4 * 8;
      ABu pk;
      #pragma unroll
      for (int j = 0; j < 4; j++)
        pk.u[j] = f2bbits(wr[2 * j]) | (f2bbits(wr[2 * j + 1]) << 16);
      af[ot][kt] = pk.v;
    }
  }
  __syncthreads();

  f32x4 acc[3][8];
  #pragma unroll
  for (int ot = 0; ot < 3; ot++)
    #pragma unroll
    for (int pt = 0; pt < 8; pt++) acc[ot][pt] = (f32x4){0.f,0.f,0.f,0.f};

  #pragma unroll
  for (int pt = 0; pt < 8; pt++){
    uint4 u0 = xs[(0 * 4 + g4) * 128 + pt * 16 + r16];
    uint4 u1 = xs[(1 * 4 + g4) * 128 + pt * 16 + r16];
    bf16x8 b0 = *reinterpret_cast<bf16x8*>(&u0);
    bf16x8 b1 = *reinterpret_cast<bf16x8*>(&u1);
    #pragma unroll
    for (int ot = 0; ot < 3; ot++){
      acc[ot][pt] = __builtin_amdgcn_mfma_f32_16x16x32_bf16(af[ot][0], b0, acc[ot][pt], 0, 0, 0);
      acc[ot][pt] = __builtin_amdgcn_mfma_f32_16x16x32_bf16(af[ot][1], b1, acc[ot][pt], 0, 0, 0);
    }
  }

  bf16* op = qkv1 + (size_t)b * 192 * HWSZ + hw0;
  #pragma unroll
  for (int ot = 0; ot < 3; ot++){
    int ochb = (w * 3 + ot) * 16 + g4 * 4;
    #pragma unroll
    for (int pt = 0; pt < 8; pt++)
      #pragma unroll
      for (int r = 0; r < 4; r++)
        op[(size_t)(ochb + r) * HWSZ + pt * 16 + r16] = f2b(acc[ot][pt][r]);
  }
}

// ---------------- K2 (v4): 3x3 depthwise conv + tokenize, full-line reads
__global__ __launch_bounds__(256) void k2_dwconv_tok(
    const bf16* __restrict__ qkv1, const float* __restrict__ wdw, bf16* __restrict__ tok){
  int t = threadIdx.x;
  u32 n = blockIdx.x;
  u32 bid = (n & 7u) * 384u + (n >> 3);     // XCD swizzle (3072 = 8*384, bijective)
  u32 wx2 = bid & 3u, yb = (bid >> 2) & 15u, g = (bid >> 6) % 3u, b = bid / 192u;
  int c = t & 63, rq = t >> 6;              // 64 ch x 4 row-quads
  int y0 = (int)(yb * 16u) + rq * 4;
  int x0 = (int)(wx2 * 64u);

  const float* wp = wdw + ((size_t)g * 64 + c) * 9;
  float w0=wp[0],w1=wp[1],w2=wp[2],w3=wp[3],w4=wp[4],w5=wp[5],w6=wp[6],w7=wp[7],w8=wp[8];

  const bf16* src = qkv1 + ((size_t)b * 192 + g * 64 + c) * HWSZ;

  int h = 4 * (int)(yb & 1u) + rq;
  size_t base = ((((((size_t)g * 16 + b) * 8 + h) * 64)
                + (size_t)(yb >> 1) * 8 + wx2 * 2) * 8192) + (size_t)c;
  bf16* op = tok + base;

  uint4 rb[3][8];
  float Lh[3], Rh[3];

  #define LDROW(s, yy) do{                                            \
    int _y = (yy);                                                    \
    if ((u32)_y < 256u){                                              \
      const bf16* _p = src + (_y << 8) + x0;                          \
      _Pragma("unroll")                                               \
      for (int _j = 0; _j < 8; _j++) rb[s][_j] = *(const uint4*)(_p + _j * 8); \
      Lh[s] = (x0 > 0)        ? b2f(_p[-1]) : 0.f;                    \
      Rh[s] = (x0 + 64 < 256) ? b2f(_p[64]) : 0.f;                    \
    } else {                                                          \
      _Pragma("unroll")                                               \
      for (int _j = 0; _j < 8; _j++) rb[s][_j] = make_uint4(0u,0u,0u,0u); \
      Lh[s] = 0.f; Rh[s] = 0.f;                                       \
    }                                                                 \
  }while(0)

  LDROW(0, y0 - 1);
  LDROW(1, y0);
  LDROW(2, y0 + 1);

  #pragma unroll
  for (int rr = 0; rr < 4; rr++){
    const int sT = rr % 3, sM = (rr + 1) % 3, sB = (rr + 2) % 3;
    const u32* uT = (const u32*)rb[sT];
    const u32* uM = (const u32*)rb[sM];
    const u32* uB = (const u32*)rb[sB];
    float lT = Lh[sT], mT = b2f_lo(uT[0]);
    float lM = Lh[sM], mM = b2f_lo(uM[0]);
    float lB = Lh[sB], mB = b2f_lo(uB[0]);
    #pragma unroll
    for (int j = 0; j < 64; j++){
      float rT, rM, rB;
      if (j < 63){
        int e = j + 1;
        u32 xT = uT[e >> 1], xM = uM[e >> 1], xB = uB[e >> 1];
        if (e & 1){ rT = b2f_hi(xT); rM = b2f_hi(xM); rB = b2f_hi(xB); }
        else      { rT = b2f_lo(xT); rM = b2f_lo(xM); rB = b2f_lo(xB); }
      } else { rT = Rh[sT]; rM = Rh[sM]; rB = Rh[sB]; }
      float acc = lT*w0 + mT*w1 + rT*w2
                + lM*w3 + mM*w4 + rM*w5
                + lB*w6 + mB*w7 + rB*w8;
      op[(size_t)rr * 2048 + (j >> 5) * 8192 + (j & 31) * 64] = f2b(acc);
      lT = mT; mT = rT; lM = mM; mM = rM; lB = mB; mB = rB;
    }
    if (rr < 3){
      LDROW(sT, y0 + rr + 2);
    }
  }
  #undef LDROW
}

// ---------------- K3 (MFMA): sim partials over d-quarter -> sim4[part][b][h][64][64]
// block = (b,h,part), 4 waves; wave w owns i-tile w (16 rows) x all 4 j-tiles.
__global__ __launch_bounds__(256) void k3_sim(
    const bf16* __restrict__ tok, float* __restrict__ sim4){
  __shared__ short qs[64 * 72];              // 64 tokens x 72 elems (144B rows, padded)
  __shared__ short ks[64 * 72];
  int t = threadIdx.x;
  int lane = t & 63, w = t >> 6;
  int r16 = lane & 15, g4 = lane >> 4;
  u32 bid = blockIdx.x;
  u32 part = bid & 3u, h = (bid >> 2) & 7u, b = bid >> 5;
  const bf16* qb = tok + ((size_t)(((0 * 16 + b) * 8 + h) * 64)) * 8192 + part * 2048;
  const bf16* kb = tok + ((size_t)(((1 * 16 + b) * 8 + h) * 64)) * 8192 + part * 2048;

  int stok = t >> 2, soct = t & 3;           // staging: token row, 16B octet

  f32x4 acc[4];
  #pragma unroll
  for (int jt = 0; jt < 4; jt++) acc[jt] = (f32x4){0.f,0.f,0.f,0.f};

  for (int s = 0; s < 32; s++){
    int d0 = s * 64;
    __syncthreads();
    {
      uint4 q0 = *(const uint4*)(qb + (size_t)stok * 8192 + d0 + soct * 8);
      uint4 q1 = *(const uint4*)(qb + (size_t)stok * 8192 + d0 + soct * 8 + 32);
      uint4 k0 = *(const uint4*)(kb + (size_t)stok * 8192 + d0 + soct * 8);
      uint4 k1 = *(const uint4*)(kb + (size_t)stok * 8192 + d0 + soct * 8 + 32);
      *(uint4*)&qs[stok * 72 + soct * 8]      = q0;
      *(uint4*)&qs[stok * 72 + soct * 8 + 32] = q1;
      *(uint4*)&ks[stok * 72 + soct * 8]      = k0;
      *(uint4*)&ks[stok * 72 + soct * 8 + 32] = k1;
    }
    __syncthreads();
    #pragma unroll
    for (int kt = 0; kt < 2; kt++){
      bf16x8 a = *(const bf16x8*)&qs[(w * 16 + r16) * 72 + kt * 32 + g4 * 8];
      #pragma unroll
      for (int jt = 0; jt < 4; jt++){
        bf16x8 bb = *(const bf16x8*)&ks[(jt * 16 + r16) * 72 + kt * 32 + g4 * 8];
        acc[jt] = __builtin_amdgcn_mfma_f32_16x16x32_bf16(a, bb, acc[jt], 0, 0, 0);
      }
    }
  }

  float* sp = sim4 + ((((size_t)part * 16 + b) * 8 + h) * 64) * 64;
  #pragma unroll
  for (int jt = 0; jt < 4; jt++)
    #pragma unroll
    for (int r = 0; r < 4; r++)
      sp[(w * 16 + g4 * 4 + r) * 64 + jt * 16 + r16] = acc[jt][r];
}

// ---------------- K4: combine partials, scale, +pos_emb, softmax (unchanged)
__global__ __launch_bounds__(64) void k4_softmax(
    const float* __restrict__ sim4, const float* __restrict__ pos, float* __restrict__ attn){
  int j = threadIdx.x;
  u32 bid = blockIdx.x;
  u32 i = bid & 63u, h = (bid >> 6) & 7u, b = bid >> 9;
  size_t o = (((size_t)b * 8 + h) * 64 + i) * 64 + j;
  const size_t pstride = (size_t)16 * 8 * 64 * 64;
  float s = sim4[o] + sim4[o + pstride] + sim4[o + 2 * pstride] + sim4[o + 3 * pstride];
  s = s * 0.011048543456039806f + pos[(((size_t)h * 64) + i) * 64 + j];
  float m = s;
  #pragma unroll
  for (int off = 32; off; off >>= 1) m = fmaxf(m, __shfl_xor(m, off));
  float e = __expf(s - m);
  float sum = e;
  #pragma unroll
  for (int off = 32; off; off >>= 1) sum += __shfl_xor(sum, off);
  attn[o] = e / sum;
}

// ---------------- K5 (MFMA): otok[i,d] = sum_j attn[i,j] * V[j,d]
// block = (b,h,quarter), 4 waves, no barriers; wave w owns d-slices of 64 within
// its 512-d range. V transposed per-wave into LDS (VT[d][j]); attn rows in regs.
__global__ __launch_bounds__(256) void k5_av(
    const bf16* __restrict__ tok, const float* __restrict__ attn, bf16* __restrict__ otok){
  __shared__ short vt[4][64 * 72];           // per-wave private: 64 d-rows x 72 (j) elems
  int t = threadIdx.x;
  int lane = t & 63, w = t >> 6;
  int r16 = lane & 15, g4 = lane >> 4;
  u32 bid = blockIdx.x;
  u32 q = bid & 3u, h = (bid >> 2) & 7u, b = bid >> 5;
  const bf16* vb = tok + ((size_t)(((2 * 16 + b) * 8 + h) * 64)) * 8192;
  const float* ab = attn + (((size_t)b * 8 + h) * 64) * 64;
  bf16* ob = otok + (((size_t)b * 8 + h) * 64) * 8192;

  // A-fragments: attn rows, bf16. a[it][kt]: A[i = it*16+r16][j = kt*32+g4*8 ..+7]
  bf16x8 af[4][2];
  #pragma unroll
  for (int it = 0; it < 4; it++)
    #pragma unroll
    for (int kt = 0; kt < 2; kt++){
      const float* ar = ab + (it * 16 + r16) * 64 + kt * 32 + g4 * 8;
      ABu pk;
      #pragma unroll
      for (int j = 0; j < 4; j++)
        pk.u[j] = f2bbits(ar[2 * j]) | (f2bbits(ar[2 * j + 1]) << 16);
      af[it][kt] = pk.v;
    }

  short* vtw = vt[w];
  for (int s = 0; s < 8; s++){
    int d0 = (int)q * 2048 + s * 256 + w * 64;   // this wave's 64-d slice
    // load V[j=lane][d0..d0+63] (full 128B row) and transpose into vtw[d][j]
    uint4 ld[8];
    const bf16* vp = vb + (size_t)lane * 8192 + d0;
    #pragma unroll
    for (int u = 0; u < 8; u++) ld[u] = *(const uint4*)(vp + u * 8);
    #pragma unroll
    for (int u = 0; u < 8; u++){
      const u32* wd = (const u32*)&ld[u];
      #pragma unroll
      for (int e = 0; e < 4; e++){
        int d = u * 8 + e * 2;
        vtw[d * 72 + lane]       = (short)(wd[e] & 0xffffu);
        vtw[(d + 1) * 72 + lane] = (short)(wd[e] >> 16);
      }
    }
    // compute 16 tiles (4 it x 4 dt), K=64 in 2 MFMAs
    #pragma unroll
    for (int dt = 0; dt < 4; dt++){
      bf16x8 b0 = *(const bf16x8*)&vtw[(dt * 16 + r16) * 72 + 0 * 32 + g4 * 8];
      bf16x8 b1 = *(const bf16x8*)&vtw[(dt * 16 + r16) * 72 + 1 * 32 + g4 * 8];
      #pragma unroll
      for (int it = 0; it < 4; it++){
        f32x4 acc = (f32x4){0.f,0.f,0.f,0.f};
        acc = __builtin_amdgcn_mfma_f32_16x16x32_bf16(af[it][0], b0, acc, 0, 0, 0);
        acc = __builtin_amdgcn_mfma_f32_16x16x32_bf16(af[it][1], b1, acc, 0, 0, 0);
        #pragma unroll
        for (int r = 0; r < 4; r++)
          ob[(size_t)(it * 16 + g4 * 4 + r) * 8192 + d0 + dt * 16 + r16] = f2b(acc[r]);
      }
    }
  }
}

// ---------------- K6 (MFMA): out[b,64,HW] fp32 = Wp[64,64] x OT[64,HW] + bias
__global__ __launch_bounds__(256) void k6_mfma(
    const bf16* __restrict__ otok, const float* __restrict__ wp,
    const float* __restrict__ bp, float* __restrict__ out){
  __shared__ uint4 xs[1024];
  int t = threadIdx.x;
  int lane = t & 63, w = t >> 6;
  u32 pix0 = blockIdx.x * 128u;
  u32 b = pix0 >> 16, hw0 = pix0 & 65535u;
  int y = (int)(hw0 >> 8);
  int p0 = y & 31, h = p0 >> 2, prow = (p0 & 3) * 2048;
  int iy = (y >> 5) << 3;

  {
    int pix = t & 127, half = t >> 7;
    int xx = (int)(hw0 & 255u) + pix;
    int i = iy + (xx >> 5), p1 = xx & 31;
    const bf16* ip = otok + ((((size_t)b * 8 + h) * 64 + i)) * 8192 + prow + p1 * 64;
    #pragma unroll
    for (int g = 0; g < 4; g++){
      int c8 = half * 4 + g;
      xs[c8 * 128 + pix] = *(const uint4*)(ip + c8 * 8);
    }
  }

  int r16 = lane & 15, g4 = lane >> 4;
  bf16x8 af[2];
  int och = w * 16 + r16;
  #pragma unroll
  for (int kt = 0; kt < 2; kt++){
    const float* wr = wp + och * 64 + kt * 32 + g4 * 8;
    ABu pk;
    #pragma unroll
    for (int j = 0; j < 4; j++)
      pk.u[j] = f2bbits(wr[2 * j]) | (f2bbits(wr[2 * j + 1]) << 16);
    af[kt] = pk.v;
  }
  float bias[4];
  #pragma unroll
  for (int r = 0; r < 4; r++) bias[r] = bp[w * 16 + g4 * 4 + r];
  __syncthreads();

  f32x4 acc[8];
  #pragma unroll
  for (int pt = 0; pt < 8; pt++) acc[pt] = (f32x4){bias[0], bias[1], bias[2], bias[3]};

  #pragma unroll
  for (int pt = 0; pt < 8; pt++){
    uint4 u0 = xs[(0 * 4 + g4) * 128 + pt * 16 + r16];
    uint4 u1 = xs[(1 * 4 + g4) * 128 + pt * 16 + r16];
    bf16x8 b0 = *reinterpret_cast<bf16x8*>(&u0);
    bf16x8 b1 = *reinterpret_cast<bf16x8*>(&u1);
    acc[pt] = __builtin_amdgcn_mfma_f32_16x16x32_bf16(af[0], b0, acc[pt], 0, 0, 0);
    acc[pt] = __builtin_amdgcn_mfma_f32_16x16x32_bf16(af[1], b1, acc[pt], 0, 0, 0);
  }

  float* op = out + (size_t)b * 64 * HWSZ + hw0;
  int ochb = w * 16 + g4 * 4;
  #pragma unroll
  for (int pt = 0; pt < 8; pt++)
    #pragma unroll
    for (int r = 0; r < 4; r++)
      op[(size_t)(ochb + r) * HWSZ + pt * 16 + r16] = acc[pt][r];
}

extern "C" void kernel_launch(void* const* d_in, const int* in_sizes, int n_in,
                              void* d_out, int out_size, void* d_ws, size_t ws_size,
                              hipStream_t stream){
  const float* x   = (const float*)d_in[0];
  const float* wq  = (const float*)d_in[1];
  const float* wdw = (const float*)d_in[2];
  const float* wp  = (const float*)d_in[3];
  const float* bp  = (const float*)d_in[4];
  const float* pos = (const float*)d_in[5];
  float* out = (float*)d_out;
  (void)in_sizes; (void)n_in; (void)out_size; (void)ws_size;

  char* ws = (char*)d_ws;
  bf16*  qkv1 = (bf16*)ws;
  bf16*  tok  = (bf16*)(ws + 402653184u);
  bf16*  otok = (bf16*)ws;                  // region A reuse after K2
  float* sim4 = (float*)(ws + 134217728u);
  float* attn = (float*)(ws + 142606336u);

  k1_mfma<<<dim3(8192),  dim3(256), 0, stream>>>(x, wq, qkv1);
  k2_dwconv_tok<<<dim3(3072), dim3(256), 0, stream>>>(qkv1, wdw, tok);
  k3_sim<<<dim3(512),   dim3(256), 0, stream>>>(tok, sim4);
  k4_softmax<<<dim3(8192), dim3(64), 0, stream>>>(sim4, pos, attn);
  k5_av<<<dim3(512),  dim3(256), 0, stream>>>(tok, attn, otok);
  k6_mfma<<<dim3(8192), dim3(256), 0, stream>>>(otok, wp, bp, out);
}

// Round 6
// 524.720 us; speedup vs baseline: 3.7458x; 1.2793x over previous
//
#include <hip/hip_runtime.h>
#include <hip/hip_bf16.h>

typedef __hip_bfloat16 bf16;
typedef unsigned int u32;
typedef __attribute__((ext_vector_type(8))) short bf16x8;
typedef __attribute__((ext_vector_type(4))) float f32x4;

#define HWSZ 65536u   // 256*256

__device__ __forceinline__ float b2f_lo(u32 w){ return __uint_as_float(w << 16); }
__device__ __forceinline__ float b2f_hi(u32 w){ return __uint_as_float(w & 0xffff0000u); }
__device__ __forceinline__ float b2f(bf16 v){ return __bfloat162float(v); }
__device__ __forceinline__ bf16 f2b(float v){ return __float2bfloat16(v); }

__device__ __forceinline__ u32 f2bbits(float f){
  u32 x = __float_as_uint(f);
  return ((x + 0x7fffu + ((x >> 16) & 1u)) >> 16) & 0xffffu;  // RNE
}

__device__ __forceinline__ void unpack8(uint4 v, float* f){
  f[0]=b2f_lo(v.x); f[1]=b2f_hi(v.x);
  f[2]=b2f_lo(v.y); f[3]=b2f_hi(v.y);
  f[4]=b2f_lo(v.z); f[5]=b2f_hi(v.z);
  f[6]=b2f_lo(v.w); f[7]=b2f_hi(v.w);
}

union ABu { u32 u[4]; bf16x8 v; uint4 q; };

// ---------------- K12 (fused): pointwise qkv (MFMA) + 3x3 depthwise + tokenize
// block = (b, yt 16-row band, xt 8-col strip). Region = 18 rows x 10 cols (halo'd),
// px = rr*10+cr in [0,180), padded to 192 (12 MFMA n-tiles).
// xs: x as bf16 [c8=8][px=192] 16B units, XOR-swizzled unit index.
// qs: qkv for current g, [px=192][och 64 + pad4] bf16.
__global__ __launch_bounds__(256) void k12_fused(
    const float* __restrict__ x, const float* __restrict__ wq,
    const float* __restrict__ wdw, bf16* __restrict__ tok){
  __shared__ uint4 xs[8 * 192];              // 24.0 KB
  __shared__ unsigned short qs[192 * 68];    // 25.5 KB
  int t = threadIdx.x;
  int lane = t & 63, w = t >> 6;
  int r16 = lane & 15, g4 = lane >> 4;

  u32 n = blockIdx.x;
  u32 bid = (n & 7u) * 1024u + (n >> 3);     // XCD swizzle (8192 = 8*1024, bijective)
  u32 xt = bid & 31u, yt = (bid >> 5) & 15u, b = bid >> 9;
  int y0 = (int)yt * 16, x0 = (int)xt * 8;

  const float* xb = x + (size_t)b * 64 * HWSZ;

  // A fragments (W rows) for all 3 g, loaded up-front
  bf16x8 af[3][2];
  #pragma unroll
  for (int g = 0; g < 3; g++){
    int och = g * 64 + w * 16 + r16;
    #pragma unroll
    for (int kt = 0; kt < 2; kt++){
      const float* wr = wq + och * 64 + kt * 32 + g4 * 8;
      ABu pk;
      #pragma unroll
      for (int j = 0; j < 4; j++)
        pk.u[j] = f2bbits(wr[2 * j]) | (f2bbits(wr[2 * j + 1]) << 16);
      af[g][kt] = pk.v;
    }
  }

  // ---- stage x: 288 units = (c8, rr in [0,18), jh in {0,1}); unit = 4 ch x 10 cols
  for (int u = t; u < 288; u += 256){
    int jh = u & 1, rr = (u >> 1) % 18, c8 = u / 36;
    int yy = y0 - 1 + rr;
    float va[4][10];
    if ((u32)yy < 256u){
      #pragma unroll
      for (int jc = 0; jc < 4; jc++){
        const float* p = xb + (size_t)(c8 * 8 + jh * 4 + jc) * HWSZ + ((size_t)yy << 8);
        float4 A  = *(const float4*)(p + x0);        // 16B-aligned (x0 % 8 == 0)
        float4 Bq = *(const float4*)(p + x0 + 4);
        va[jc][0] = (x0 > 0) ? p[x0 - 1] : 0.f;
        va[jc][1] = A.x;  va[jc][2] = A.y;  va[jc][3] = A.z;  va[jc][4] = A.w;
        va[jc][5] = Bq.x; va[jc][6] = Bq.y; va[jc][7] = Bq.z; va[jc][8] = Bq.w;
        va[jc][9] = (x0 + 8 < 256) ? p[x0 + 8] : 0.f;
      }
    } else {
      #pragma unroll
      for (int jc = 0; jc < 4; jc++)
        #pragma unroll
        for (int e = 0; e < 10; e++) va[jc][e] = 0.f;
    }
    #pragma unroll
    for (int e = 0; e < 10; e++){
      u32 w0 = f2bbits(va[0][e]) | (f2bbits(va[1][e]) << 16);
      u32 w1 = f2bbits(va[2][e]) | (f2bbits(va[3][e]) << 16);
      int a16 = c8 * 192 + rr * 10 + e;
      a16 = (a16 & ~7) | ((a16 ^ (a16 >> 3)) & 7);   // XOR bank swizzle
      ((uint2*)&xs[a16])[jh] = make_uint2(w0, w1);
    }
  }
  if (t < 96){                                        // zero-pad px 180..191
    int c8 = t / 12, px = 180 + (t % 12);
    int a16 = c8 * 192 + px;
    a16 = (a16 & ~7) | ((a16 ^ (a16 >> 3)) & 7);
    xs[a16] = make_uint4(0u, 0u, 0u, 0u);
  }

  int cth = t & 63, rq = w;                           // dwconv decomposition
  int h = (int)(yt & 1u) * 4 + rq;
  u32 win = (yt >> 1) * 8u + (xt >> 2);

  for (int g = 0; g < 3; g++){
    __syncthreads();                                  // xs ready / qs free
    // ---- pointwise MFMA: wave w owns och-tile w (16 rows of 64), 12 n-tiles
    #pragma unroll
    for (int nt = 0; nt < 12; nt++){
      f32x4 acc = (f32x4){0.f, 0.f, 0.f, 0.f};
      #pragma unroll
      for (int kt = 0; kt < 2; kt++){
        int a16 = (kt * 4 + g4) * 192 + nt * 16 + r16;
        a16 = (a16 & ~7) | ((a16 ^ (a16 >> 3)) & 7);
        uint4 uq = xs[a16];
        acc = __builtin_amdgcn_mfma_f32_16x16x32_bf16(
            af[g][kt], *reinterpret_cast<bf16x8*>(&uq), acc, 0, 0, 0);
      }
      int px = nt * 16 + r16;
      u32 lo = f2bbits(acc[0]) | (f2bbits(acc[1]) << 16);
      u32 hi = f2bbits(acc[2]) | (f2bbits(acc[3]) << 16);
      *(uint2*)&qs[px * 68 + w * 16 + g4 * 4] = make_uint2(lo, hi);
    }
    __syncthreads();                                  // qs ready

    // ---- depthwise 3x3 + tokenized store
    const float* wg = wdw + ((size_t)g * 64 + cth) * 9;
    float d0=wg[0],d1=wg[1],d2=wg[2],d3=wg[3],d4=wg[4],d5=wg[5],d6=wg[6],d7=wg[7],d8=wg[8];
    bf16* op = tok + (((((size_t)g * 16 + b) * 8 + h) * 64 + win) * 8192)
             + (size_t)(xt & 3u) * 512 + cth;
    float rbf[3][10];
    #define QLD(s, R) do{ _Pragma("unroll") for (int _cr = 0; _cr < 10; _cr++) \
      rbf[s][_cr] = __uint_as_float(((u32)qs[((R) * 10 + _cr) * 68 + cth]) << 16); }while(0)
    QLD(0, rq * 4 + 0);
    QLD(1, rq * 4 + 1);
    QLD(2, rq * 4 + 2);
    #pragma unroll
    for (int rr2 = 0; rr2 < 4; rr2++){
      const int sT = rr2 % 3, sM = (rr2 + 1) % 3, sB = (rr2 + 2) % 3;
      #pragma unroll
      for (int co = 0; co < 8; co++){
        float o = rbf[sT][co]*d0 + rbf[sT][co+1]*d1 + rbf[sT][co+2]*d2
                + rbf[sM][co]*d3 + rbf[sM][co+1]*d4 + rbf[sM][co+2]*d5
                + rbf[sB][co]*d6 + rbf[sB][co+1]*d7 + rbf[sB][co+2]*d8;
        op[(size_t)rr2 * 2048 + co * 64] = f2b(o);
      }
      if (rr2 < 3) QLD(sT, rq * 4 + rr2 + 3);
    }
    #undef QLD
  }
}

// ---------------- K3 (MFMA): sim partials over d-quarter -> sim4[part][b][h][64][64]
__global__ __launch_bounds__(256) void k3_sim(
    const bf16* __restrict__ tok, float* __restrict__ sim4){
  __shared__ short qs[64 * 72];
  __shared__ short ks[64 * 72];
  int t = threadIdx.x;
  int lane = t & 63, w = t >> 6;
  int r16 = lane & 15, g4 = lane >> 4;
  u32 bid = blockIdx.x;
  u32 part = bid & 3u, h = (bid >> 2) & 7u, b = bid >> 5;
  const bf16* qb = tok + ((size_t)(((0 * 16 + b) * 8 + h) * 64)) * 8192 + part * 2048;
  const bf16* kb = tok + ((size_t)(((1 * 16 + b) * 8 + h) * 64)) * 8192 + part * 2048;

  int stok = t >> 2, soct = t & 3;

  f32x4 acc[4];
  #pragma unroll
  for (int jt = 0; jt < 4; jt++) acc[jt] = (f32x4){0.f,0.f,0.f,0.f};

  for (int s = 0; s < 32; s++){
    int d0 = s * 64;
    __syncthreads();
    {
      uint4 q0 = *(const uint4*)(qb + (size_t)stok * 8192 + d0 + soct * 8);
      uint4 q1 = *(const uint4*)(qb + (size_t)stok * 8192 + d0 + soct * 8 + 32);
      uint4 k0 = *(const uint4*)(kb + (size_t)stok * 8192 + d0 + soct * 8);
      uint4 k1 = *(const uint4*)(kb + (size_t)stok * 8192 + d0 + soct * 8 + 32);
      *(uint4*)&qs[stok * 72 + soct * 8]      = q0;
      *(uint4*)&qs[stok * 72 + soct * 8 + 32] = q1;
      *(uint4*)&ks[stok * 72 + soct * 8]      = k0;
      *(uint4*)&ks[stok * 72 + soct * 8 + 32] = k1;
    }
    __syncthreads();
    #pragma unroll
    for (int kt = 0; kt < 2; kt++){
      bf16x8 a = *(const bf16x8*)&qs[(w * 16 + r16) * 72 + kt * 32 + g4 * 8];
      #pragma unroll
      for (int jt = 0; jt < 4; jt++){
        bf16x8 bb = *(const bf16x8*)&ks[(jt * 16 + r16) * 72 + kt * 32 + g4 * 8];
        acc[jt] = __builtin_amdgcn_mfma_f32_16x16x32_bf16(a, bb, acc[jt], 0, 0, 0);
      }
    }
  }

  float* sp = sim4 + ((((size_t)part * 16 + b) * 8 + h) * 64) * 64;
  #pragma unroll
  for (int jt = 0; jt < 4; jt++)
    #pragma unroll
    for (int r = 0; r < 4; r++)
      sp[(w * 16 + g4 * 4 + r) * 64 + jt * 16 + r16] = acc[jt][r];
}

// ---------------- K4: combine partials, scale, +pos_emb, softmax
__global__ __launch_bounds__(64) void k4_softmax(
    const float* __restrict__ sim4, const float* __restrict__ pos, float* __restrict__ attn){
  int j = threadIdx.x;
  u32 bid = blockIdx.x;
  u32 i = bid & 63u, h = (bid >> 6) & 7u, b = bid >> 9;
  size_t o = (((size_t)b * 8 + h) * 64 + i) * 64 + j;
  const size_t pstride = (size_t)16 * 8 * 64 * 64;
  float s = sim4[o] + sim4[o + pstride] + sim4[o + 2 * pstride] + sim4[o + 3 * pstride];
  s = s * 0.011048543456039806f + pos[(((size_t)h * 64) + i) * 64 + j];
  float m = s;
  #pragma unroll
  for (int off = 32; off; off >>= 1) m = fmaxf(m, __shfl_xor(m, off));
  float e = __expf(s - m);
  float sum = e;
  #pragma unroll
  for (int off = 32; off; off >>= 1) sum += __shfl_xor(sum, off);
  attn[o] = e / sum;
}

// ---------------- K5 (MFMA): otok[i,d] = sum_j attn[i,j] * V[j,d]
__global__ __launch_bounds__(256) void k5_av(
    const bf16* __restrict__ tok, const float* __restrict__ attn, bf16* __restrict__ otok){
  __shared__ short vt[4][64 * 72];
  int t = threadIdx.x;
  int lane = t & 63, w = t >> 6;
  int r16 = lane & 15, g4 = lane >> 4;
  u32 bid = blockIdx.x;
  u32 q = bid & 3u, h = (bid >> 2) & 7u, b = bid >> 5;
  const bf16* vb = tok + ((size_t)(((2 * 16 + b) * 8 + h) * 64)) * 8192;
  const float* ab = attn + (((size_t)b * 8 + h) * 64) * 64;
  bf16* ob = otok + (((size_t)b * 8 + h) * 64) * 8192;

  bf16x8 af[4][2];
  #pragma unroll
  for (int it = 0; it < 4; it++)
    #pragma unroll
    for (int kt = 0; kt < 2; kt++){
      const float* ar = ab + (it * 16 + r16) * 64 + kt * 32 + g4 * 8;
      ABu pk;
      #pragma unroll
      for (int j = 0; j < 4; j++)
        pk.u[j] = f2bbits(ar[2 * j]) | (f2bbits(ar[2 * j + 1]) << 16);
      af[it][kt] = pk.v;
    }

  short* vtw = vt[w];
  for (int s = 0; s < 8; s++){
    int d0 = (int)q * 2048 + s * 256 + w * 64;
    uint4 ld[8];
    const bf16* vp = vb + (size_t)lane * 8192 + d0;
    #pragma unroll
    for (int u = 0; u < 8; u++) ld[u] = *(const uint4*)(vp + u * 8);
    #pragma unroll
    for (int u = 0; u < 8; u++){
      const u32* wd = (const u32*)&ld[u];
      #pragma unroll
      for (int e = 0; e < 4; e++){
        int d = u * 8 + e * 2;
        vtw[d * 72 + lane]       = (short)(wd[e] & 0xffffu);
        vtw[(d + 1) * 72 + lane] = (short)(wd[e] >> 16);
      }
    }
    #pragma unroll
    for (int dt = 0; dt < 4; dt++){
      bf16x8 b0 = *(const bf16x8*)&vtw[(dt * 16 + r16) * 72 + 0 * 32 + g4 * 8];
      bf16x8 b1 = *(const bf16x8*)&vtw[(dt * 16 + r16) * 72 + 1 * 32 + g4 * 8];
      #pragma unroll
      for (int it = 0; it < 4; it++){
        f32x4 acc = (f32x4){0.f,0.f,0.f,0.f};
        acc = __builtin_amdgcn_mfma_f32_16x16x32_bf16(af[it][0], b0, acc, 0, 0, 0);
        acc = __builtin_amdgcn_mfma_f32_16x16x32_bf16(af[it][1], b1, acc, 0, 0, 0);
        #pragma unroll
        for (int r = 0; r < 4; r++)
          ob[(size_t)(it * 16 + g4 * 4 + r) * 8192 + d0 + dt * 16 + r16] = f2b(acc[r]);
      }
    }
  }
}

// ---------------- K6 (MFMA): out[b,64,HW] fp32 = Wp[64,64] x OT[64,HW] + bias
__global__ __launch_bounds__(256) void k6_mfma(
    const bf16* __restrict__ otok, const float* __restrict__ wp,
    const float* __restrict__ bp, float* __restrict__ out){
  __shared__ uint4 xs[1024];
  int t = threadIdx.x;
  int lane = t & 63, w = t >> 6;
  u32 pix0 = blockIdx.x * 128u;
  u32 b = pix0 >> 16, hw0 = pix0 & 65535u;
  int y = (int)(hw0 >> 8);
  int p0 = y & 31, h = p0 >> 2, prow = (p0 & 3) * 2048;
  int iy = (y >> 5) << 3;

  {
    int pix = t & 127, half = t >> 7;
    int xx = (int)(hw0 & 255u) + pix;
    int i = iy + (xx >> 5), p1 = xx & 31;
    const bf16* ip = otok + ((((size_t)b * 8 + h) * 64 + i)) * 8192 + prow + p1 * 64;
    #pragma unroll
    for (int g = 0; g < 4; g++){
      int c8 = half * 4 + g;
      xs[c8 * 128 + pix] = *(const uint4*)(ip + c8 * 8);
    }
  }

  int r16 = lane & 15, g4 = lane >> 4;
  bf16x8 af[2];
  int och = w * 16 + r16;
  #pragma unroll
  for (int kt = 0; kt < 2; kt++){
    const float* wr = wp + och * 64 + kt * 32 + g4 * 8;
    ABu pk;
    #pragma unroll
    for (int j = 0; j < 4; j++)
      pk.u[j] = f2bbits(wr[2 * j]) | (f2bbits(wr[2 * j + 1]) << 16);
    af[kt] = pk.v;
  }
  float bias[4];
  #pragma unroll
  for (int r = 0; r < 4; r++) bias[r] = bp[w * 16 + g4 * 4 + r];
  __syncthreads();

  f32x4 acc[8];
  #pragma unroll
  for (int pt = 0; pt < 8; pt++) acc[pt] = (f32x4){bias[0], bias[1], bias[2], bias[3]};

  #pragma unroll
  for (int pt = 0; pt < 8; pt++){
    uint4 u0 = xs[(0 * 4 + g4) * 128 + pt * 16 + r16];
    uint4 u1 = xs[(1 * 4 + g4) * 128 + pt * 16 + r16];
    bf16x8 b0 = *reinterpret_cast<bf16x8*>(&u0);
    bf16x8 b1 = *reinterpret_cast<bf16x8*>(&u1);
    acc[pt] = __builtin_amdgcn_mfma_f32_16x16x32_bf16(af[0], b0, acc[pt], 0, 0, 0);
    acc[pt] = __builtin_amdgcn_mfma_f32_16x16x32_bf16(af[1], b1, acc[pt], 0, 0, 0);
  }

  float* op = out + (size_t)b * 64 * HWSZ + hw0;
  int ochb = w * 16 + g4 * 4;
  #pragma unroll
  for (int pt = 0; pt < 8; pt++)
    #pragma unroll
    for (int r = 0; r < 4; r++)
      op[(size_t)(ochb + r) * HWSZ + pt * 16 + r16] = acc[pt][r];
}

extern "C" void kernel_launch(void* const* d_in, const int* in_sizes, int n_in,
                              void* d_out, int out_size, void* d_ws, size_t ws_size,
                              hipStream_t stream){
  const float* x   = (const float*)d_in[0];
  const float* wq  = (const float*)d_in[1];
  const float* wdw = (const float*)d_in[2];
  const float* wp  = (const float*)d_in[3];
  const float* bp  = (const float*)d_in[4];
  const float* pos = (const float*)d_in[5];
  float* out = (float*)d_out;
  (void)in_sizes; (void)n_in; (void)out_size; (void)ws_size;

  char* ws = (char*)d_ws;
  bf16*  tok  = (bf16*)(ws + 402653184u);
  bf16*  otok = (bf16*)ws;
  float* sim4 = (float*)(ws + 134217728u);
  float* attn = (float*)(ws + 142606336u);

  k12_fused<<<dim3(8192), dim3(256), 0, stream>>>(x, wq, wdw, tok);
  k3_sim<<<dim3(512),   dim3(256), 0, stream>>>(tok, sim4);
  k4_softmax<<<dim3(8192), dim3(64), 0, stream>>>(sim4, pos, attn);
  k5_av<<<dim3(512),  dim3(256), 0, stream>>>(tok, attn, otok);
  k6_mfma<<<dim3(8192), dim3(256), 0, stream>>>(otok, wp, bp, out);
}